// Round 1
// baseline (2894.552 us; speedup 1.0000x reference)
//
#include <hip/hip_runtime.h>
#include <math.h>

// Problem constants (B=2,S=1024,D=2048,H=16,HD=128,ROT=64,LQ=1024,LKV=512,ED=1024,E=8,TOPK=2)
#define TT   2048   // B*S tokens
#define DM   2048
#define SEQ  1024
#define NH   16
#define HDIM 128
#define RDIM 64
#define NE   8

__device__ __forceinline__ float gelu_f(float x) {
  return 0.5f * x * (1.0f + erff(x * 0.7071067811865476f));
}

__device__ __forceinline__ float block_sum(float v, float* red) {
#pragma unroll
  for (int m = 32; m; m >>= 1) v += __shfl_xor(v, m);
  __syncthreads();                       // protect red reuse across calls
  if ((threadIdx.x & 63) == 0) red[threadIdx.x >> 6] = v;
  __syncthreads();
  return red[0] + red[1] + red[2] + red[3];
}

// ---------------- RMSNorm ----------------
__global__ __launch_bounds__(256) void rms_k(const float* __restrict__ x,
                                             const float* __restrict__ w,
                                             float* __restrict__ out) {
  __shared__ float red[4];
  const int t = blockIdx.x, tid = threadIdx.x;
  const float* xr = x + (size_t)t * DM;
  float4 v0 = *(const float4*)&xr[tid * 4];
  float4 v1 = *(const float4*)&xr[1024 + tid * 4];
  float ss = v0.x*v0.x + v0.y*v0.y + v0.z*v0.z + v0.w*v0.w
           + v1.x*v1.x + v1.y*v1.y + v1.z*v1.z + v1.w*v1.w;
  float s = block_sum(ss, red);
  float r = rsqrtf(s * (1.0f / DM) + 1e-6f);
  float4 w0 = *(const float4*)&w[tid * 4];
  float4 w1 = *(const float4*)&w[1024 + tid * 4];
  float* orow = out + (size_t)t * DM;
  *(float4*)&orow[tid * 4] = make_float4(v0.x*r*w0.x, v0.y*r*w0.y, v0.z*r*w0.z, v0.w*r*w0.w);
  *(float4*)&orow[1024 + tid * 4] = make_float4(v1.x*r*w1.x, v1.y*r*w1.y, v1.z*r*w1.z, v1.w*r*w1.w);
}

// double RMS: hn = rms(rms(x,w2), wm)
__global__ __launch_bounds__(256) void rms2_k(const float* __restrict__ x,
                                              const float* __restrict__ w2,
                                              const float* __restrict__ wm,
                                              float* __restrict__ out) {
  __shared__ float red[4];
  const int t = blockIdx.x, tid = threadIdx.x;
  const float* xr = x + (size_t)t * DM;
  float4 v0 = *(const float4*)&xr[tid * 4];
  float4 v1 = *(const float4*)&xr[1024 + tid * 4];
  float ss = v0.x*v0.x + v0.y*v0.y + v0.z*v0.z + v0.w*v0.w
           + v1.x*v1.x + v1.y*v1.y + v1.z*v1.z + v1.w*v1.w;
  float s1 = block_sum(ss, red);
  float r1 = rsqrtf(s1 * (1.0f / DM) + 1e-6f);
  float4 a0 = *(const float4*)&w2[tid * 4];
  float4 a1 = *(const float4*)&w2[1024 + tid * 4];
  float4 y0 = make_float4(v0.x*r1*a0.x, v0.y*r1*a0.y, v0.z*r1*a0.z, v0.w*r1*a0.w);
  float4 y1 = make_float4(v1.x*r1*a1.x, v1.y*r1*a1.y, v1.z*r1*a1.z, v1.w*r1*a1.w);
  float ss2 = y0.x*y0.x + y0.y*y0.y + y0.z*y0.z + y0.w*y0.w
            + y1.x*y1.x + y1.y*y1.y + y1.z*y1.z + y1.w*y1.w;
  float s2 = block_sum(ss2, red);
  float r2 = rsqrtf(s2 * (1.0f / DM) + 1e-6f);
  float4 b0 = *(const float4*)&wm[tid * 4];
  float4 b1 = *(const float4*)&wm[1024 + tid * 4];
  float* orow = out + (size_t)t * DM;
  *(float4*)&orow[tid * 4] = make_float4(y0.x*r2*b0.x, y0.y*r2*b0.y, y0.z*r2*b0.z, y0.w*r2*b0.w);
  *(float4*)&orow[1024 + tid * 4] = make_float4(y1.x*r2*b1.x, y1.y*r2*b1.y, y1.z*r2*b1.z, y1.w*r2*b1.w);
}

// ---------------- SGEMM: C(MxN) = A(MxK,row) * B(KxN,row) [+bias][+res][gelu] ----------------
// tile 64x64, 256 threads, 4x4 microtile. M,N multiples of 64; K multiple of 16.
template <int ACT, bool BIAS, bool RES>
__global__ __launch_bounds__(256) void gemm_k(const float* __restrict__ A, int lda,
                                              const float* __restrict__ Bm, int ldb,
                                              float* __restrict__ C, int ldc, int K,
                                              const float* __restrict__ bias,
                                              const float* __restrict__ res, int ldr) {
  __shared__ float As[16][68];  // [k][m], stride 68 breaks bank pattern, keeps 16B align
  __shared__ float Bs[16][64];  // [k][n]
  const int tid = threadIdx.x;
  const int bm = blockIdx.y * 64, bn = blockIdx.x * 64;
  const int tm = ((tid >> 4) & 15) * 4;
  const int tn = (tid & 15) * 4;
  const int ar = tid >> 2, ak = (tid & 3) * 4;
  const int bk = tid >> 4, bn4 = (tid & 15) * 4;
  const float* Ap = A + (size_t)(bm + ar) * lda + ak;
  const float* Bp = Bm + (size_t)bk * ldb + bn + bn4;
  float acc[4][4] = {};
  for (int k0 = 0; k0 < K; k0 += 16) {
    float4 a4 = *(const float4*)(Ap + k0);
    float4 b4 = *(const float4*)(Bp + (size_t)k0 * ldb);
    As[ak + 0][ar] = a4.x;
    As[ak + 1][ar] = a4.y;
    As[ak + 2][ar] = a4.z;
    As[ak + 3][ar] = a4.w;
    *(float4*)&Bs[bk][bn4] = b4;
    __syncthreads();
#pragma unroll
    for (int kk = 0; kk < 16; ++kk) {
      float4 av = *(const float4*)&As[kk][tm];
      float4 bv = *(const float4*)&Bs[kk][tn];
      float aa[4] = {av.x, av.y, av.z, av.w};
      float bb[4] = {bv.x, bv.y, bv.z, bv.w};
#pragma unroll
      for (int i = 0; i < 4; ++i)
#pragma unroll
        for (int j = 0; j < 4; ++j) acc[i][j] = fmaf(aa[i], bb[j], acc[i][j]);
    }
    __syncthreads();
  }
  float4 bv4 = make_float4(0.f, 0.f, 0.f, 0.f);
  if (BIAS) bv4 = *(const float4*)&bias[bn + tn];
#pragma unroll
  for (int i = 0; i < 4; ++i) {
    const int row = bm + tm + i;
    float o0 = acc[i][0], o1 = acc[i][1], o2 = acc[i][2], o3 = acc[i][3];
    if (BIAS) { o0 += bv4.x; o1 += bv4.y; o2 += bv4.z; o3 += bv4.w; }
    if (RES) {
      float4 r4 = *(const float4*)&res[(size_t)row * ldr + bn + tn];
      o0 += r4.x; o1 += r4.y; o2 += r4.z; o3 += r4.w;
    }
    if (ACT == 1) { o0 = gelu_f(o0); o1 = gelu_f(o1); o2 = gelu_f(o2); o3 = gelu_f(o3); }
    *(float4*)&C[(size_t)row * ldc + bn + tn] = make_float4(o0, o1, o2, o3);
  }
}

// ---------------- grouped expert GEMM ----------------
// expert e = blockIdx.z; rows are entries [base[e], base[e]+cnt[e]).
// GATHER: A row = entry_token[entry] (token rows of hn). else A row = entry (mid).
template <bool GATHER, int ACT>
__global__ __launch_bounds__(256) void gemm_grp_k(const float* __restrict__ A, int lda,
                                                  const float* __restrict__ Ball, int K, int N,
                                                  float* __restrict__ C,
                                                  const float* __restrict__ biasAll,
                                                  const int* __restrict__ counts,
                                                  const int* __restrict__ bases,
                                                  const int* __restrict__ entry_token) {
  const int e = blockIdx.z;
  const int cnt = counts[e];
  const int m0 = blockIdx.y * 64;
  if (m0 >= cnt) return;
  const int base = bases[e];
  const int bn = blockIdx.x * 64;
  const float* Bm = Ball + (size_t)e * K * N;
  const float* bias = biasAll + (size_t)e * N;
  __shared__ float As[16][68];
  __shared__ float Bs[16][64];
  const int tid = threadIdx.x;
  const int tm = ((tid >> 4) & 15) * 4;
  const int tn = (tid & 15) * 4;
  const int ar = tid >> 2, ak = (tid & 3) * 4;
  const int bk = tid >> 4, bn4 = (tid & 15) * 4;
  const bool avalid = (m0 + ar) < cnt;
  int arow;
  if (GATHER) arow = avalid ? entry_token[base + m0 + ar] : 0;
  else        arow = base + m0 + ar;
  const float* Ap = A + (size_t)arow * lda + ak;
  const float* Bp = Bm + (size_t)bk * N + bn + bn4;
  float acc[4][4] = {};
  for (int k0 = 0; k0 < K; k0 += 16) {
    float4 a4 = make_float4(0.f, 0.f, 0.f, 0.f);
    if (avalid) a4 = *(const float4*)(Ap + k0);
    float4 b4 = *(const float4*)(Bp + (size_t)k0 * N);
    As[ak + 0][ar] = a4.x;
    As[ak + 1][ar] = a4.y;
    As[ak + 2][ar] = a4.z;
    As[ak + 3][ar] = a4.w;
    *(float4*)&Bs[bk][bn4] = b4;
    __syncthreads();
#pragma unroll
    for (int kk = 0; kk < 16; ++kk) {
      float4 av = *(const float4*)&As[kk][tm];
      float4 bv = *(const float4*)&Bs[kk][tn];
      float aa[4] = {av.x, av.y, av.z, av.w};
      float bb[4] = {bv.x, bv.y, bv.z, bv.w};
#pragma unroll
      for (int i = 0; i < 4; ++i)
#pragma unroll
        for (int j = 0; j < 4; ++j) acc[i][j] = fmaf(aa[i], bb[j], acc[i][j]);
    }
    __syncthreads();
  }
  float4 bv4 = *(const float4*)&bias[bn + tn];
#pragma unroll
  for (int i = 0; i < 4; ++i) {
    const int r = m0 + tm + i;
    if (r >= cnt) continue;
    float o0 = acc[i][0] + bv4.x, o1 = acc[i][1] + bv4.y;
    float o2 = acc[i][2] + bv4.z, o3 = acc[i][3] + bv4.w;
    if (ACT == 1) { o0 = gelu_f(o0); o1 = gelu_f(o1); o2 = gelu_f(o2); o3 = gelu_f(o3); }
    *(float4*)&C[(size_t)(base + r) * N + bn + tn] = make_float4(o0, o1, o2, o3);
  }
}

// ---------------- RoPE (in place, interleaved pairs) ----------------
__global__ __launch_bounds__(256) void rope_k(float* __restrict__ buf,
                                              const float* __restrict__ cosb,
                                              const float* __restrict__ sinb) {
  const int i = blockIdx.x * 256 + threadIdx.x;  // pair index over TT*NH*32
  if (i >= TT * NH * 32) return;
  const int t = i >> 9;            // / (NH*32)
  const int rem = i & 511;
  const int hh = rem >> 5, p = rem & 31;
  const int s = t & (SEQ - 1);
  const float c = cosb[s * 32 + p], sn = sinb[s * 32 + p];
  float* ptr = buf + (size_t)t * (NH * RDIM) + hh * RDIM + p * 2;
  const float x0 = ptr[0], x1 = ptr[1];
  ptr[0] = x0 * c - x1 * sn;
  ptr[1] = x0 * sn + x1 * c;
}

// ---------------- flash attention (fp32), 32 q-rows per block ----------------
__global__ __launch_bounds__(256) void attn_k(const float* __restrict__ qb,
                                              const float* __restrict__ qrb,
                                              const float* __restrict__ kb,
                                              const float* __restrict__ krb,
                                              const float* __restrict__ vb,
                                              float* __restrict__ ob) {
  __shared__ float Qs[32][196];
  __shared__ float Ks[32][196];
  __shared__ float Vs[32][160];   // swizzled: col d stored at d + (d/16)*4
  __shared__ float Ps[32][33];
  __shared__ float scale_s[32], l_s[32];
  const int tid = threadIdx.x;
  const int hh = blockIdx.y, bb = blockIdx.z;
  const int q0 = blockIdx.x * 32;
  const int tbase = bb * SEQ;

  for (int idx = tid; idx < 32 * 48; idx += 256) {
    const int r = idx / 48, c4 = idx % 48;
    const int tkn = tbase + q0 + r;
    float4 val = (c4 < 32)
        ? *(const float4*)&qb[(size_t)tkn * DM + hh * HDIM + c4 * 4]
        : *(const float4*)&qrb[(size_t)tkn * (NH * RDIM) + hh * RDIM + (c4 - 32) * 4];
    *(float4*)&Qs[r][c4 * 4] = val;
  }

  const int q4 = tid >> 5, kj = tid & 31;  // S-phase mapping
  const int qi = tid >> 3, dd = tid & 7;   // PV-phase mapping
  float m_run[4], l_run[4], O[16];
#pragma unroll
  for (int r = 0; r < 4; ++r) { m_run[r] = -3.0e38f; l_run[r] = 0.f; }
#pragma unroll
  for (int j = 0; j < 16; ++j) O[j] = 0.f;

  for (int kt = 0; kt < SEQ / 32; ++kt) {
    __syncthreads();  // Qs ready / previous PV done
    for (int idx = tid; idx < 32 * 48; idx += 256) {
      const int r = idx / 48, c4 = idx % 48;
      const int tkn = tbase + kt * 32 + r;
      float4 val = (c4 < 32)
          ? *(const float4*)&kb[(size_t)tkn * DM + hh * HDIM + c4 * 4]
          : *(const float4*)&krb[(size_t)tkn * (NH * RDIM) + hh * RDIM + (c4 - 32) * 4];
      *(float4*)&Ks[r][c4 * 4] = val;
    }
    for (int idx = tid; idx < 32 * 32; idx += 256) {
      const int r = idx >> 5, c4 = idx & 31;
      const int d0 = c4 * 4;
      float4 val = *(const float4*)&vb[(size_t)(tbase + kt * 32 + r) * DM + hh * HDIM + d0];
      *(float4*)&Vs[r][d0 + (d0 >> 4) * 4] = val;
    }
    __syncthreads();

    // S = Q K^T * scale (each thread: 4 q-rows x 1 key)
    float sv[4] = {0.f, 0.f, 0.f, 0.f};
#pragma unroll 8
    for (int d = 0; d < 192; d += 4) {
      float4 kv = *(const float4*)&Ks[kj][d];
#pragma unroll
      for (int r = 0; r < 4; ++r) {
        float4 qv = *(const float4*)&Qs[q4 * 4 + r][d];
        sv[r] = fmaf(qv.x, kv.x, sv[r]);
        sv[r] = fmaf(qv.y, kv.y, sv[r]);
        sv[r] = fmaf(qv.z, kv.z, sv[r]);
        sv[r] = fmaf(qv.w, kv.w, sv[r]);
      }
    }
#pragma unroll
    for (int r = 0; r < 4; ++r) {
      float s = sv[r] * 0.07216878364870322f;  // 1/sqrt(192)
      float mt = s;
#pragma unroll
      for (int m = 16; m; m >>= 1) mt = fmaxf(mt, __shfl_xor(mt, m));
      const float m_new = fmaxf(m_run[r], mt);
      const float pexp = __expf(s - m_new);
      float rs = pexp;
#pragma unroll
      for (int m = 16; m; m >>= 1) rs += __shfl_xor(rs, m);
      const float sc = __expf(m_run[r] - m_new);
      l_run[r] = l_run[r] * sc + rs;
      m_run[r] = m_new;
      Ps[q4 * 4 + r][kj] = pexp;
      if (kj == 0) scale_s[q4 * 4 + r] = sc;
    }
    __syncthreads();

    // PV (each thread: 1 q-row x 16 v-dims)
    const float scv = scale_s[qi];
#pragma unroll
    for (int j = 0; j < 16; ++j) O[j] *= scv;
#pragma unroll 4
    for (int k2 = 0; k2 < 32; ++k2) {
      const float pv = Ps[qi][k2];
      const float* vrow = &Vs[k2][dd * 20];
#pragma unroll
      for (int j4 = 0; j4 < 4; ++j4) {
        float4 vv = *(const float4*)&vrow[j4 * 4];
        O[j4 * 4 + 0] = fmaf(pv, vv.x, O[j4 * 4 + 0]);
        O[j4 * 4 + 1] = fmaf(pv, vv.y, O[j4 * 4 + 1]);
        O[j4 * 4 + 2] = fmaf(pv, vv.z, O[j4 * 4 + 2]);
        O[j4 * 4 + 3] = fmaf(pv, vv.w, O[j4 * 4 + 3]);
      }
    }
  }
  if (kj == 0) {
#pragma unroll
    for (int r = 0; r < 4; ++r) l_s[q4 * 4 + r] = l_run[r];
  }
  __syncthreads();
  const float linv = 1.f / l_s[qi];
  float* orow = &ob[(size_t)(tbase + q0 + qi) * DM + hh * HDIM + dd * 16];
#pragma unroll
  for (int j4 = 0; j4 < 4; ++j4) {
    *(float4*)&orow[j4 * 4] = make_float4(O[j4 * 4 + 0] * linv, O[j4 * 4 + 1] * linv,
                                          O[j4 * 4 + 2] * linv, O[j4 * 4 + 3] * linv);
  }
}

// ---------------- router: softmax over 8 experts + top2 ----------------
__global__ __launch_bounds__(256) void router_k(const float* __restrict__ hn,
                                                const float* __restrict__ cent,
                                                int* __restrict__ topk_idx,
                                                float* __restrict__ topk_w,
                                                int* __restrict__ pos,
                                                int* __restrict__ counts) {
  const int t = blockIdx.x, tid = threadIdx.x;
  float p[NE] = {};
  const float* xr = hn + (size_t)t * DM;
  for (int d = tid * 4; d < DM; d += 1024) {
    float4 xv = *(const float4*)&xr[d];
#pragma unroll
    for (int e = 0; e < NE; ++e) {
      float4 cv = *(const float4*)&cent[e * DM + d];
      p[e] += xv.x * cv.x + xv.y * cv.y + xv.z * cv.z + xv.w * cv.w;
    }
  }
  __shared__ float wred[NE][4];
#pragma unroll
  for (int e = 0; e < NE; ++e) {
    float v = p[e];
#pragma unroll
    for (int m = 32; m; m >>= 1) v += __shfl_xor(v, m);
    if ((tid & 63) == 0) wred[e][tid >> 6] = v;
  }
  __syncthreads();
  if (tid == 0) {
    float lg[NE], mx = -3.0e38f;
    for (int e = 0; e < NE; ++e) {
      lg[e] = wred[e][0] + wred[e][1] + wred[e][2] + wred[e][3];
      mx = fmaxf(mx, lg[e]);
    }
    float pe[NE], sum = 0.f;
    for (int e = 0; e < NE; ++e) { pe[e] = expf(lg[e] - mx); sum += pe[e]; }
    const float inv = 1.f / sum;
    int i0 = 0; float v0 = -1.f;
    for (int e = 0; e < NE; ++e) { float a = pe[e] * inv; if (a > v0) { v0 = a; i0 = e; } }
    int i1 = 0; float v1 = -1.f;
    for (int e = 0; e < NE; ++e) { if (e == i0) continue; float a = pe[e] * inv; if (a > v1) { v1 = a; i1 = e; } }
    topk_idx[t * 2 + 0] = i0;
    topk_idx[t * 2 + 1] = i1;
    topk_w[t * 2 + 0] = v0;
    topk_w[t * 2 + 1] = v1;
    pos[t * 2 + 0] = atomicAdd(&counts[i0], 1);
    pos[t * 2 + 1] = atomicAdd(&counts[i1], 1);
  }
}

// ---------------- prefix + scatter (1 block) ----------------
__global__ __launch_bounds__(256) void scatter_k(const int* __restrict__ topk_idx,
                                                 const int* __restrict__ pos,
                                                 const int* __restrict__ counts,
                                                 int* __restrict__ bases,
                                                 int* __restrict__ entry_token,
                                                 int* __restrict__ token_entry) {
  __shared__ int sb[NE];
  const int tid = threadIdx.x;
  if (tid == 0) {
    int acc = 0;
    for (int e = 0; e < NE; ++e) { sb[e] = acc; bases[e] = acc; acc += counts[e]; }
  }
  __syncthreads();
  for (int i = tid; i < TT * 2; i += 256) {
    const int e = topk_idx[i];
    const int entry = sb[e] + pos[i];
    entry_token[entry] = i >> 1;
    token_entry[i] = entry;
  }
}

// ---------------- final combine: out = x2 + hn + shared + w0*oute[e0] + w1*oute[e1] ----------------
__global__ __launch_bounds__(256) void combine_k(const float* __restrict__ x2,
                                                 const float* __restrict__ hn,
                                                 const float* __restrict__ sh,
                                                 const float* __restrict__ oute,
                                                 const int* __restrict__ token_entry,
                                                 const float* __restrict__ topk_w,
                                                 float* __restrict__ out) {
  const int i = blockIdx.x * 256 + threadIdx.x;  // float4 index
  const int t = i >> 9;
  const int c = (i & 511) * 4;
  const int e0 = token_entry[t * 2 + 0], e1 = token_entry[t * 2 + 1];
  const float w0 = topk_w[t * 2 + 0], w1 = topk_w[t * 2 + 1];
  float4 a = *(const float4*)&x2[(size_t)t * DM + c];
  float4 b = *(const float4*)&hn[(size_t)t * DM + c];
  float4 s = *(const float4*)&sh[(size_t)t * DM + c];
  float4 r0 = *(const float4*)&oute[(size_t)e0 * DM + c];
  float4 r1 = *(const float4*)&oute[(size_t)e1 * DM + c];
  *(float4*)&out[(size_t)t * DM + c] =
      make_float4(a.x + b.x + s.x + w0 * r0.x + w1 * r1.x,
                  a.y + b.y + s.y + w0 * r0.y + w1 * r1.y,
                  a.z + b.z + s.z + w0 * r0.z + w1 * r1.z,
                  a.w + b.w + s.w + w0 * r0.w + w1 * r1.w);
}

// ---------------- host ----------------
extern "C" void kernel_launch(void* const* d_in, const int* in_sizes, int n_in,
                              void* d_out, int out_size, void* d_ws, size_t ws_size,
                              hipStream_t stream) {
  (void)in_sizes; (void)n_in; (void)out_size; (void)ws_size;
  const float* x       = (const float*)d_in[0];
  const float* fc      = (const float*)d_in[1];
  const float* fs      = (const float*)d_in[2];
  const float* w_norm1 = (const float*)d_in[3];
  const float* w_lq    = (const float*)d_in[4];
  const float* w_lkv   = (const float*)d_in[5];
  const float* w_q     = (const float*)d_in[6];
  const float* w_k     = (const float*)d_in[7];
  const float* w_v     = (const float*)d_in[8];
  const float* w_qr    = (const float*)d_in[9];
  const float* b_qr    = (const float*)d_in[10];
  const float* w_kr    = (const float*)d_in[11];
  const float* b_kr    = (const float*)d_in[12];
  const float* w_o     = (const float*)d_in[13];
  const float* b_o     = (const float*)d_in[14];
  const float* w_norm2 = (const float*)d_in[15];
  const float* w_moe   = (const float*)d_in[16];
  const float* cent    = (const float*)d_in[17];
  const float* ws1     = (const float*)d_in[18];
  const float* bs1     = (const float*)d_in[19];
  const float* ws2     = (const float*)d_in[20];
  const float* bs2     = (const float*)d_in[21];
  const float* wr1     = (const float*)d_in[22];
  const float* br1     = (const float*)d_in[23];
  const float* wr2     = (const float*)d_in[24];
  const float* br2     = (const float*)d_in[25];
  float* out = (float*)d_out;

  float* W = (float*)d_ws;
  const size_t M1 = 1u << 20;
  float* h     = W;             // 4M
  float* cq    = W + 4 * M1;    // 2M
  float* ckv   = W + 6 * M1;    // 1M
  float* qbuf  = W + 7 * M1;    // 4M
  float* qrbuf = W + 11 * M1;   // 2M
  float* krbuf = W + 13 * M1;   // 2M
  float* vbuf  = W + 15 * M1;   // 4M
  float* kbuf  = W + 19 * M1;   // 4M
  float* obuf  = W + 23 * M1;   // 4M
  float* x2    = W + 27 * M1;   // 4M
  float* hn    = W + 31 * M1;   // 4M  (total 35M floats = 140MB)
  // aliases of dead buffers:
  float* s1b   = cq;            // 2M, cq dead after q/qr GEMMs
  float* shb   = qbuf;          // 4M, qbuf dead after attention
  float* oute  = qrbuf;         // 8M, spans qrbuf+krbuf+vbuf (dead after attention)
  float* midb  = kbuf;          // 4M, kbuf dead after attention
  int* ip          = (int*)(W + 35 * M1);
  int* counts      = ip;
  int* bases       = ip + 8;
  int* topk_idx    = ip + 16;
  int* pos         = ip + 16 + 4096;
  int* token_entry = ip + 16 + 8192;
  int* entry_token = ip + 16 + 12288;
  float* topk_w    = (float*)(ip + 16 + 16384);

  // 1. h = rms(x, w_norm1)
  rms_k<<<TT, 256, 0, stream>>>(x, w_norm1, h);
  // 2-3. cq, ckv
  gemm_k<0, false, false><<<dim3(16, 32), 256, 0, stream>>>(h, DM, w_lq, 1024, cq, 1024, DM, nullptr, nullptr, 0);
  gemm_k<0, false, false><<<dim3(8, 32), 256, 0, stream>>>(h, DM, w_lkv, 512, ckv, 512, DM, nullptr, nullptr, 0);
  // 4-8. q, qr, k, kr, v
  gemm_k<0, false, false><<<dim3(32, 32), 256, 0, stream>>>(cq, 1024, w_q, DM, qbuf, DM, 1024, nullptr, nullptr, 0);
  gemm_k<0, true, false><<<dim3(16, 32), 256, 0, stream>>>(cq, 1024, w_qr, 1024, qrbuf, 1024, 1024, b_qr, nullptr, 0);
  gemm_k<0, false, false><<<dim3(32, 32), 256, 0, stream>>>(ckv, 512, w_k, DM, kbuf, DM, 512, nullptr, nullptr, 0);
  gemm_k<0, true, false><<<dim3(16, 32), 256, 0, stream>>>(h, DM, w_kr, 1024, krbuf, 1024, DM, b_kr, nullptr, 0);
  gemm_k<0, false, false><<<dim3(32, 32), 256, 0, stream>>>(ckv, 512, w_v, DM, vbuf, DM, 512, nullptr, nullptr, 0);
  // 9. RoPE in place
  rope_k<<<4096, 256, 0, stream>>>(qrbuf, fc, fs);
  rope_k<<<4096, 256, 0, stream>>>(krbuf, fc, fs);
  // 10. attention
  attn_k<<<dim3(32, NH, 2), 256, 0, stream>>>(qbuf, qrbuf, kbuf, krbuf, vbuf, obuf);
  // 11. x2 = x + o @ w_o + b_o
  gemm_k<0, true, true><<<dim3(32, 32), 256, 0, stream>>>(obuf, DM, w_o, DM, x2, DM, DM, b_o, x, DM);
  // 12. hn = rms(rms(x2, w_norm2), w_moe_norm)
  rms2_k<<<TT, 256, 0, stream>>>(x2, w_norm2, w_moe, hn);
  // 13-14. shared FFN
  gemm_k<0, true, false><<<dim3(16, 32), 256, 0, stream>>>(hn, DM, ws1, 1024, s1b, 1024, DM, bs1, nullptr, 0);
  gemm_k<1, true, false><<<dim3(32, 32), 256, 0, stream>>>(s1b, 1024, ws2, DM, shb, DM, 1024, bs2, nullptr, 0);
  // 15-16. router + scatter
  hipMemsetAsync(counts, 0, NE * sizeof(int), stream);
  router_k<<<TT, 256, 0, stream>>>(hn, cent, topk_idx, topk_w, pos, counts);
  scatter_k<<<1, 256, 0, stream>>>(topk_idx, pos, counts, bases, entry_token, token_entry);
  // 17-18. grouped expert GEMMs (top-2 sparse)
  gemm_grp_k<true, 0><<<dim3(16, 32, NE), 256, 0, stream>>>(hn, DM, wr1, DM, 1024, midb, br1, counts, bases, entry_token);
  gemm_grp_k<false, 1><<<dim3(32, 32, NE), 256, 0, stream>>>(midb, 1024, wr2, 1024, DM, oute, br2, counts, bases, nullptr);
  // 19. combine
  combine_k<<<4096, 256, 0, stream>>>(x2, hn, shb, oute, token_entry, topk_w, out);
}

// Round 2
// 905.028 us; speedup vs baseline: 3.1983x; 3.1983x over previous
//
#include <hip/hip_runtime.h>
#include <math.h>

// B=2,S=1024,D=2048,H=16,HD=128,ROT=64,LQ=1024,LKV=512,ED=1024,E=8,TOPK=2
#define TT   2048
#define DM   2048
#define SEQ  1024
#define NH   16
#define NE   8
#define MB_  (1024*1024)
#define ATT_SCALE 0.07216878364870322f   // 1/sqrt(192)

typedef unsigned short u16;
typedef __attribute__((ext_vector_type(8))) short s8v;   // 8 x bf16 (4 VGPR)
typedef __attribute__((ext_vector_type(4))) float f4v;   // MFMA acc

__device__ __forceinline__ u16 f2bf(float f) {
  unsigned u = __builtin_bit_cast(unsigned, f);
  unsigned r = (u + 0x7fffu + ((u >> 16) & 1u)) >> 16;   // RNE
  return (u16)r;
}
__device__ __forceinline__ float bf2f(u16 h) {
  return __builtin_bit_cast(float, (unsigned)h << 16);
}
__device__ __forceinline__ float gelu_f(float x) {
  return 0.5f * x * (1.0f + erff(x * 0.7071067811865476f));
}
__device__ __forceinline__ f4v mfma16(s8v a, s8v b, f4v c) {
  return __builtin_amdgcn_mfma_f32_16x16x32_bf16(a, b, c, 0, 0, 0);
}

// ---------------- transpose + cast: src fp32 [R][C] -> dst bf16 [C][R] ----------------
__global__ __launch_bounds__(256) void tcast_k(const float* __restrict__ src,
                                               u16* __restrict__ dst, int R, int C) {
  __shared__ float tile[32][33];
  const size_t bofs = (size_t)blockIdx.z * R * C;
  src += bofs; dst += bofs;
  const int r0 = blockIdx.y * 32, c0 = blockIdx.x * 32;
  const int t = threadIdx.x;
  const int tr = t >> 3, tc4 = (t & 7) * 4;
  float4 v = *(const float4*)&src[(size_t)(r0 + tr) * C + c0 + tc4];
  tile[tr][tc4 + 0] = v.x; tile[tr][tc4 + 1] = v.y;
  tile[tr][tc4 + 2] = v.z; tile[tr][tc4 + 3] = v.w;
  __syncthreads();
  ushort4 o;
  o.x = f2bf(tile[tc4 + 0][tr]);
  o.y = f2bf(tile[tc4 + 1][tr]);
  o.z = f2bf(tile[tc4 + 2][tr]);
  o.w = f2bf(tile[tc4 + 3][tr]);
  *(ushort4*)&dst[(size_t)(c0 + tr) * R + r0 + tc4] = o;
}

__device__ __forceinline__ float block_sum(float v, float* red) {
#pragma unroll
  for (int m = 32; m; m >>= 1) v += __shfl_xor(v, m);
  __syncthreads();
  if ((threadIdx.x & 63) == 0) red[threadIdx.x >> 6] = v;
  __syncthreads();
  return red[0] + red[1] + red[2] + red[3];
}

// ---------------- RMSNorm -> bf16 ----------------
__global__ __launch_bounds__(256) void rmsb_k(const float* __restrict__ x,
                                              const float* __restrict__ w,
                                              u16* __restrict__ out) {
  __shared__ float red[4];
  const int t = blockIdx.x, tid = threadIdx.x;
  const float* xr = x + (size_t)t * DM;
  float4 v0 = *(const float4*)&xr[tid * 4];
  float4 v1 = *(const float4*)&xr[1024 + tid * 4];
  float ss = v0.x*v0.x + v0.y*v0.y + v0.z*v0.z + v0.w*v0.w
           + v1.x*v1.x + v1.y*v1.y + v1.z*v1.z + v1.w*v1.w;
  float s = block_sum(ss, red);
  float r = rsqrtf(s * (1.0f / DM) + 1e-6f);
  float4 w0 = *(const float4*)&w[tid * 4];
  float4 w1 = *(const float4*)&w[1024 + tid * 4];
  u16* orow = out + (size_t)t * DM;
  ushort4 o0, o1;
  o0.x = f2bf(v0.x*r*w0.x); o0.y = f2bf(v0.y*r*w0.y);
  o0.z = f2bf(v0.z*r*w0.z); o0.w = f2bf(v0.w*r*w0.w);
  o1.x = f2bf(v1.x*r*w1.x); o1.y = f2bf(v1.y*r*w1.y);
  o1.z = f2bf(v1.z*r*w1.z); o1.w = f2bf(v1.w*r*w1.w);
  *(ushort4*)&orow[tid * 4] = o0;
  *(ushort4*)&orow[1024 + tid * 4] = o1;
}

// double RMS -> fp32 + bf16
__global__ __launch_bounds__(256) void rms2_k(const float* __restrict__ x,
                                              const float* __restrict__ w2,
                                              const float* __restrict__ wm,
                                              float* __restrict__ outf,
                                              u16* __restrict__ outb) {
  __shared__ float red[4];
  const int t = blockIdx.x, tid = threadIdx.x;
  const float* xr = x + (size_t)t * DM;
  float4 v0 = *(const float4*)&xr[tid * 4];
  float4 v1 = *(const float4*)&xr[1024 + tid * 4];
  float ss = v0.x*v0.x + v0.y*v0.y + v0.z*v0.z + v0.w*v0.w
           + v1.x*v1.x + v1.y*v1.y + v1.z*v1.z + v1.w*v1.w;
  float s1 = block_sum(ss, red);
  float r1 = rsqrtf(s1 * (1.0f / DM) + 1e-6f);
  float4 a0 = *(const float4*)&w2[tid * 4];
  float4 a1 = *(const float4*)&w2[1024 + tid * 4];
  float4 y0 = make_float4(v0.x*r1*a0.x, v0.y*r1*a0.y, v0.z*r1*a0.z, v0.w*r1*a0.w);
  float4 y1 = make_float4(v1.x*r1*a1.x, v1.y*r1*a1.y, v1.z*r1*a1.z, v1.w*r1*a1.w);
  float ss2 = y0.x*y0.x + y0.y*y0.y + y0.z*y0.z + y0.w*y0.w
            + y1.x*y1.x + y1.y*y1.y + y1.z*y1.z + y1.w*y1.w;
  float s2 = block_sum(ss2, red);
  float r2 = rsqrtf(s2 * (1.0f / DM) + 1e-6f);
  float4 b0 = *(const float4*)&wm[tid * 4];
  float4 b1 = *(const float4*)&wm[1024 + tid * 4];
  float4 z0 = make_float4(y0.x*r2*b0.x, y0.y*r2*b0.y, y0.z*r2*b0.z, y0.w*r2*b0.w);
  float4 z1 = make_float4(y1.x*r2*b1.x, y1.y*r2*b1.y, y1.z*r2*b1.z, y1.w*r2*b1.w);
  float* orow = outf + (size_t)t * DM;
  *(float4*)&orow[tid * 4] = z0;
  *(float4*)&orow[1024 + tid * 4] = z1;
  u16* brow = outb + (size_t)t * DM;
  ushort4 o0, o1;
  o0.x = f2bf(z0.x); o0.y = f2bf(z0.y); o0.z = f2bf(z0.z); o0.w = f2bf(z0.w);
  o1.x = f2bf(z1.x); o1.y = f2bf(z1.y); o1.z = f2bf(z1.z); o1.w = f2bf(z1.w);
  *(ushort4*)&brow[tid * 4] = o0;
  *(ushort4*)&brow[1024 + tid * 4] = o1;
}

// ---------------- bf16 MFMA GEMM: C(MxN) = A(MxK) * Bt(NxK)^T [+bias][+res][gelu] ----
// 128x128 tile, BK=64, 4 waves each 64x64. OUT: 0=f32, 1=bf16, 2=bf16 transposed (C^T).
template <int ACT, bool BIAS, bool RES, int OUT>
__global__ __launch_bounds__(256) void bgemm_k(const u16* __restrict__ A, int lda,
                                               const u16* __restrict__ Bt, int ldb,
                                               void* __restrict__ C, int ldc, int K,
                                               const float* __restrict__ bias,
                                               const float* __restrict__ res, int ldr) {
  __shared__ u16 As[128 * 64];
  __shared__ u16 Bs[128 * 64];
  const int tid = threadIdx.x;
  const int lane = tid & 63, w = tid >> 6;
  const int wr = w >> 1, wc = w & 1;
  const int l15 = lane & 15, l4 = lane >> 4;
  const int bm = blockIdx.y * 128, bn = blockIdx.x * 128;
  int srow[4], ssw[4], scol[4];
#pragma unroll
  for (int i = 0; i < 4; ++i) {
    int q = i * 256 + tid;
    int row = q >> 3, c = q & 7;
    srow[i] = row; scol[i] = c * 8;
    ssw[i] = row * 64 + ((c ^ (row & 7)) * 8);   // bank-balanced swizzle
  }
  f4v acc[4][4] = {};
  for (int k0 = 0; k0 < K; k0 += 64) {
    s8v ra[4], rb[4];
#pragma unroll
    for (int i = 0; i < 4; ++i) {
      ra[i] = *(const s8v*)(A + (size_t)(bm + srow[i]) * lda + k0 + scol[i]);
      rb[i] = *(const s8v*)(Bt + (size_t)(bn + srow[i]) * ldb + k0 + scol[i]);
    }
    __syncthreads();
#pragma unroll
    for (int i = 0; i < 4; ++i) {
      *(s8v*)(As + ssw[i]) = ra[i];
      *(s8v*)(Bs + ssw[i]) = rb[i];
    }
    __syncthreads();
#pragma unroll
    for (int kk = 0; kk < 2; ++kk) {
      s8v af[4], bfr[4];
#pragma unroll
      for (int m = 0; m < 4; ++m) {
        int row = wr * 64 + m * 16 + l15;
        int c = kk * 4 + l4;
        af[m] = *(const s8v*)(As + row * 64 + ((c ^ (row & 7)) * 8));
      }
#pragma unroll
      for (int n = 0; n < 4; ++n) {
        int row = wc * 64 + n * 16 + l15;
        int c = kk * 4 + l4;
        bfr[n] = *(const s8v*)(Bs + row * 64 + ((c ^ (row & 7)) * 8));
      }
#pragma unroll
      for (int m = 0; m < 4; ++m)
#pragma unroll
        for (int n = 0; n < 4; ++n)
          acc[m][n] = mfma16(af[m], bfr[n], acc[m][n]);
    }
  }
#pragma unroll
  for (int m = 0; m < 4; ++m) {
    const int row0 = bm + wr * 64 + m * 16 + l4 * 4;
#pragma unroll
    for (int n = 0; n < 4; ++n) {
      const int col = bn + wc * 64 + n * 16 + l15;
      f4v v = acc[m][n];
      float bv = BIAS ? bias[col] : 0.0f;
      if (OUT == 2) {
        ushort4 o;
        o.x = f2bf(v[0] + bv); o.y = f2bf(v[1] + bv);
        o.z = f2bf(v[2] + bv); o.w = f2bf(v[3] + bv);
        *(ushort4*)((u16*)C + (size_t)col * ldc + row0) = o;
      } else {
#pragma unroll
        for (int r = 0; r < 4; ++r) {
          float o = v[r] + bv;
          if (RES) o += res[(size_t)(row0 + r) * ldr + col];
          if (ACT == 1) o = gelu_f(o);
          if (OUT == 1) ((u16*)C)[(size_t)(row0 + r) * ldc + col] = f2bf(o);
          else          ((float*)C)[(size_t)(row0 + r) * ldc + col] = o;
        }
      }
    }
  }
}

// ---------------- grouped expert bf16 GEMM (top-2 sparse) ----------------
template <bool GATHER, int ACT>
__global__ __launch_bounds__(256) void bgemm_grp_k(const u16* __restrict__ A, int lda,
                                                   const u16* __restrict__ BtAll, int K, int N,
                                                   u16* __restrict__ C,
                                                   const float* __restrict__ biasAll,
                                                   const int* __restrict__ counts,
                                                   const int* __restrict__ bases,
                                                   const int* __restrict__ entry_token) {
  const int e = blockIdx.z;
  const int cnt = counts[e];
  const int m0 = blockIdx.y * 128;
  if (m0 >= cnt) return;
  const int base = bases[e];
  const u16* Bt = BtAll + (size_t)e * K * N;
  const float* bias = biasAll + (size_t)e * N;
  __shared__ u16 As[128 * 64];
  __shared__ u16 Bs[128 * 64];
  const int tid = threadIdx.x;
  const int lane = tid & 63, w = tid >> 6;
  const int wr = w >> 1, wc = w & 1;
  const int l15 = lane & 15, l4 = lane >> 4;
  const int bn = blockIdx.x * 128;
  int arow[4], srow[4], ssw[4], scol[4];
#pragma unroll
  for (int i = 0; i < 4; ++i) {
    int q = i * 256 + tid;
    int row = q >> 3, c = q & 7;
    srow[i] = row; scol[i] = c * 8;
    ssw[i] = row * 64 + ((c ^ (row & 7)) * 8);
    int rr = m0 + row; if (rr >= cnt) rr = cnt - 1;
    arow[i] = GATHER ? entry_token[base + rr] : (base + rr);
  }
  f4v acc[4][4] = {};
  for (int k0 = 0; k0 < K; k0 += 64) {
    s8v ra[4], rb[4];
#pragma unroll
    for (int i = 0; i < 4; ++i) {
      ra[i] = *(const s8v*)(A + (size_t)arow[i] * lda + k0 + scol[i]);
      rb[i] = *(const s8v*)(Bt + (size_t)(bn + srow[i]) * K + k0 + scol[i]);
    }
    __syncthreads();
#pragma unroll
    for (int i = 0; i < 4; ++i) {
      *(s8v*)(As + ssw[i]) = ra[i];
      *(s8v*)(Bs + ssw[i]) = rb[i];
    }
    __syncthreads();
#pragma unroll
    for (int kk = 0; kk < 2; ++kk) {
      s8v af[4], bfr[4];
#pragma unroll
      for (int m = 0; m < 4; ++m) {
        int row = wr * 64 + m * 16 + l15;
        int c = kk * 4 + l4;
        af[m] = *(const s8v*)(As + row * 64 + ((c ^ (row & 7)) * 8));
      }
#pragma unroll
      for (int n = 0; n < 4; ++n) {
        int row = wc * 64 + n * 16 + l15;
        int c = kk * 4 + l4;
        bfr[n] = *(const s8v*)(Bs + row * 64 + ((c ^ (row & 7)) * 8));
      }
#pragma unroll
      for (int m = 0; m < 4; ++m)
#pragma unroll
        for (int n = 0; n < 4; ++n)
          acc[m][n] = mfma16(af[m], bfr[n], acc[m][n]);
    }
  }
#pragma unroll
  for (int m = 0; m < 4; ++m) {
    const int rl0 = m0 + wr * 64 + m * 16 + l4 * 4;
#pragma unroll
    for (int n = 0; n < 4; ++n) {
      const int col = bn + wc * 64 + n * 16 + l15;
      f4v v = acc[m][n];
      float bv = bias[col];
#pragma unroll
      for (int r = 0; r < 4; ++r) {
        const int rl = rl0 + r;
        if (rl < cnt) {
          float o = v[r] + bv;
          if (ACT == 1) o = gelu_f(o);
          C[(size_t)(base + rl) * N + col] = f2bf(o);
        }
      }
    }
  }
}

// ---------------- RoPE in place on bf16 ----------------
__global__ __launch_bounds__(256) void ropeb_k(u16* __restrict__ buf,
                                               const float* __restrict__ cosb,
                                               const float* __restrict__ sinb) {
  const int i = blockIdx.x * 256 + threadIdx.x;   // pair index over TT*NH*32
  const int t = i >> 9;
  const int rem = i & 511;
  const int hh2 = rem >> 5, p = rem & 31;
  const int s = t & (SEQ - 1);
  const float c = cosb[s * 32 + p], sn = sinb[s * 32 + p];
  unsigned* ptr = (unsigned*)(buf + (size_t)t * 1024 + hh2 * 64 + p * 2);
  unsigned vv = *ptr;
  float x0 = bf2f((u16)(vv & 0xffffu)), x1 = bf2f((u16)(vv >> 16));
  float y0 = x0 * c - x1 * sn, y1 = x0 * sn + x1 * c;
  *ptr = (unsigned)f2bf(y0) | ((unsigned)f2bf(y1) << 16);
}

// ---------------- bf16 MFMA flash attention ----------------
// grid (S/64, NH, B); 4 waves x 16 q-rows. K row-major LDS (pad 200), V pre-transposed
// global [dv][token] -> LDS [128][40]. P via per-wave LDS round-trip.
__global__ __launch_bounds__(256) void attnb_k(const u16* __restrict__ qb,
                                               const u16* __restrict__ qrb,
                                               const u16* __restrict__ kb,
                                               const u16* __restrict__ krb,
                                               const u16* __restrict__ vt,
                                               u16* __restrict__ ob) {
  __shared__ u16 Ks[32 * 200];
  __shared__ u16 Vs[128 * 40];
  __shared__ u16 Ps[4][16 * 40];
  const int tid = threadIdx.x, lane = tid & 63, w = tid >> 6;
  const int l15 = lane & 15, l4 = lane >> 4;
  const int hh = blockIdx.y, bb = blockIdx.z;
  const int tbase = bb * SEQ;
  const int q0 = blockIdx.x * 64 + w * 16;
  const int qtok = tbase + q0 + l15;
  s8v aq[6];
#pragma unroll
  for (int kc = 0; kc < 4; ++kc)
    aq[kc] = *(const s8v*)(qb + (size_t)qtok * 2048 + hh * 128 + kc * 32 + l4 * 8);
#pragma unroll
  for (int kc = 0; kc < 2; ++kc)
    aq[4 + kc] = *(const s8v*)(qrb + (size_t)qtok * 1024 + hh * 64 + kc * 32 + l4 * 8);
  f4v o[8] = {};
  float m_run[4] = {-1e30f, -1e30f, -1e30f, -1e30f};
  float l_run[4] = {0.f, 0.f, 0.f, 0.f};
  for (int kt = 0; kt < SEQ / 32; ++kt) {
    __syncthreads();
#pragma unroll
    for (int i = 0; i < 3; ++i) {                 // stage K-concat: 32 x 192
      int q = i * 256 + tid;
      int row = q / 24, c = q % 24;
      int tok = tbase + kt * 32 + row;
      s8v v;
      if (c < 16) v = *(const s8v*)(kb  + (size_t)tok * 2048 + hh * 128 + c * 8);
      else        v = *(const s8v*)(krb + (size_t)tok * 1024 + hh * 64 + (c - 16) * 8);
      *(s8v*)(Ks + row * 200 + c * 8) = v;
    }
#pragma unroll
    for (int i = 0; i < 2; ++i) {                 // stage V^T: 128 x 32
      int q = i * 256 + tid;
      int row = q >> 2, c = q & 3;
      s8v v = *(const s8v*)(vt + (size_t)(hh * 128 + row) * 2048 + tbase + kt * 32 + c * 8);
      *(s8v*)(Vs + row * 40 + c * 8) = v;
    }
    __syncthreads();
    f4v s0 = {}, s1 = {};
#pragma unroll
    for (int kc = 0; kc < 6; ++kc) {              // S = Q K^T (two 16-col tiles)
      s8v bk0 = *(const s8v*)(Ks + l15 * 200 + kc * 32 + l4 * 8);
      s8v bk1 = *(const s8v*)(Ks + (16 + l15) * 200 + kc * 32 + l4 * 8);
      s0 = mfma16(aq[kc], bk0, s0);
      s1 = mfma16(aq[kc], bk1, s1);
    }
    float scf[4];
#pragma unroll
    for (int r = 0; r < 4; ++r) {                 // online softmax, rows (l4*4+r)
      float a = s0[r] * ATT_SCALE, b = s1[r] * ATT_SCALE;
      float mt = fmaxf(a, b);
#pragma unroll
      for (int msk = 1; msk < 16; msk <<= 1) mt = fmaxf(mt, __shfl_xor(mt, msk));
      float mn = fmaxf(m_run[r], mt);
      float p0 = __expf(a - mn), p1 = __expf(b - mn);
      float rs = p0 + p1;
#pragma unroll
      for (int msk = 1; msk < 16; msk <<= 1) rs += __shfl_xor(rs, msk);
      float sc = __expf(m_run[r] - mn);
      l_run[r] = l_run[r] * sc + rs;
      m_run[r] = mn;
      scf[r] = sc;
      int rq = l4 * 4 + r;
      Ps[w][rq * 40 + l15] = f2bf(p0);
      Ps[w][rq * 40 + 16 + l15] = f2bf(p1);
    }
#pragma unroll
    for (int dt = 0; dt < 8; ++dt) {
      o[dt][0] *= scf[0]; o[dt][1] *= scf[1];
      o[dt][2] *= scf[2]; o[dt][3] *= scf[3];
    }
    s8v pa = *(const s8v*)(&Ps[w][l15 * 40 + l4 * 8]);
#pragma unroll
    for (int dt = 0; dt < 8; ++dt) {              // O += P V
      s8v bv = *(const s8v*)(Vs + (dt * 16 + l15) * 40 + l4 * 8);
      o[dt] = mfma16(pa, bv, o[dt]);
    }
  }
  float linv[4];
#pragma unroll
  for (int r = 0; r < 4; ++r) linv[r] = 1.0f / l_run[r];
#pragma unroll
  for (int dt = 0; dt < 8; ++dt)
#pragma unroll
    for (int r = 0; r < 4; ++r)
      ob[(size_t)(tbase + q0 + l4 * 4 + r) * 2048 + hh * 128 + dt * 16 + l15] =
          f2bf(o[dt][r] * linv[r]);
}

// ---------------- router: softmax over 8 experts + top2 ----------------
__global__ __launch_bounds__(256) void router_k(const float* __restrict__ hn,
                                                const float* __restrict__ cent,
                                                int* __restrict__ topk_idx,
                                                float* __restrict__ topk_w,
                                                int* __restrict__ pos,
                                                int* __restrict__ counts) {
  const int t = blockIdx.x, tid = threadIdx.x;
  float p[NE] = {};
  const float* xr = hn + (size_t)t * DM;
  for (int d = tid * 4; d < DM; d += 1024) {
    float4 xv = *(const float4*)&xr[d];
#pragma unroll
    for (int e = 0; e < NE; ++e) {
      float4 cv = *(const float4*)&cent[e * DM + d];
      p[e] += xv.x * cv.x + xv.y * cv.y + xv.z * cv.z + xv.w * cv.w;
    }
  }
  __shared__ float wred[NE][4];
#pragma unroll
  for (int e = 0; e < NE; ++e) {
    float v = p[e];
#pragma unroll
    for (int m = 32; m; m >>= 1) v += __shfl_xor(v, m);
    if ((tid & 63) == 0) wred[e][tid >> 6] = v;
  }
  __syncthreads();
  if (tid == 0) {
    float lg[NE], mx = -3.0e38f;
    for (int e = 0; e < NE; ++e) {
      lg[e] = wred[e][0] + wred[e][1] + wred[e][2] + wred[e][3];
      mx = fmaxf(mx, lg[e]);
    }
    float pe[NE], sum = 0.f;
    for (int e = 0; e < NE; ++e) { pe[e] = expf(lg[e] - mx); sum += pe[e]; }
    const float inv = 1.f / sum;
    int i0 = 0; float v0 = -1.f;
    for (int e = 0; e < NE; ++e) { float a = pe[e] * inv; if (a > v0) { v0 = a; i0 = e; } }
    int i1 = 0; float v1 = -1.f;
    for (int e = 0; e < NE; ++e) { if (e == i0) continue; float a = pe[e] * inv; if (a > v1) { v1 = a; i1 = e; } }
    topk_idx[t * 2 + 0] = i0;
    topk_idx[t * 2 + 1] = i1;
    topk_w[t * 2 + 0] = v0;
    topk_w[t * 2 + 1] = v1;
    pos[t * 2 + 0] = atomicAdd(&counts[i0], 1);
    pos[t * 2 + 1] = atomicAdd(&counts[i1], 1);
  }
}

// ---------------- prefix + scatter ----------------
__global__ __launch_bounds__(256) void scatter_k(const int* __restrict__ topk_idx,
                                                 const int* __restrict__ pos,
                                                 const int* __restrict__ counts,
                                                 int* __restrict__ bases,
                                                 int* __restrict__ entry_token,
                                                 int* __restrict__ token_entry) {
  __shared__ int sb[NE];
  const int tid = threadIdx.x;
  if (tid == 0) {
    int acc = 0;
    for (int e = 0; e < NE; ++e) { sb[e] = acc; bases[e] = acc; acc += counts[e]; }
  }
  __syncthreads();
  for (int i = tid; i < TT * 2; i += 256) {
    const int e = topk_idx[i];
    const int entry = sb[e] + pos[i];
    entry_token[entry] = i >> 1;
    token_entry[i] = entry;
  }
}

// ---------------- combine ----------------
__global__ __launch_bounds__(256) void combine_k(const float* __restrict__ x2,
                                                 const float* __restrict__ hn,
                                                 const float* __restrict__ sh,
                                                 const u16* __restrict__ oute,
                                                 const int* __restrict__ token_entry,
                                                 const float* __restrict__ topk_w,
                                                 float* __restrict__ out) {
  const int i = blockIdx.x * 256 + threadIdx.x;
  const int t = i >> 9;
  const int c = (i & 511) * 4;
  const int e0 = token_entry[t * 2 + 0], e1 = token_entry[t * 2 + 1];
  const float w0 = topk_w[t * 2 + 0], w1 = topk_w[t * 2 + 1];
  float4 a = *(const float4*)&x2[(size_t)t * DM + c];
  float4 b = *(const float4*)&hn[(size_t)t * DM + c];
  float4 s = *(const float4*)&sh[(size_t)t * DM + c];
  ushort4 u0 = *(const ushort4*)&oute[(size_t)e0 * DM + c];
  ushort4 u1 = *(const ushort4*)&oute[(size_t)e1 * DM + c];
  *(float4*)&out[(size_t)t * DM + c] =
      make_float4(a.x + b.x + s.x + w0 * bf2f(u0.x) + w1 * bf2f(u1.x),
                  a.y + b.y + s.y + w0 * bf2f(u0.y) + w1 * bf2f(u1.y),
                  a.z + b.z + s.z + w0 * bf2f(u0.z) + w1 * bf2f(u1.z),
                  a.w + b.w + s.w + w0 * bf2f(u0.w) + w1 * bf2f(u1.w));
}

// ---------------- host ----------------
extern "C" void kernel_launch(void* const* d_in, const int* in_sizes, int n_in,
                              void* d_out, int out_size, void* d_ws, size_t ws_size,
                              hipStream_t stream) {
  (void)in_sizes; (void)n_in; (void)out_size; (void)ws_size;
  const float* x       = (const float*)d_in[0];
  const float* fc      = (const float*)d_in[1];
  const float* fs      = (const float*)d_in[2];
  const float* w_norm1 = (const float*)d_in[3];
  const float* w_lq    = (const float*)d_in[4];
  const float* w_lkv   = (const float*)d_in[5];
  const float* w_q     = (const float*)d_in[6];
  const float* w_k     = (const float*)d_in[7];
  const float* w_v     = (const float*)d_in[8];
  const float* w_qr    = (const float*)d_in[9];
  const float* b_qr    = (const float*)d_in[10];
  const float* w_kr    = (const float*)d_in[11];
  const float* b_kr    = (const float*)d_in[12];
  const float* w_o     = (const float*)d_in[13];
  const float* b_o     = (const float*)d_in[14];
  const float* w_norm2 = (const float*)d_in[15];
  const float* w_moe   = (const float*)d_in[16];
  const float* cent    = (const float*)d_in[17];
  const float* ws1     = (const float*)d_in[18];
  const float* bs1     = (const float*)d_in[19];
  const float* ws2     = (const float*)d_in[20];
  const float* bs2     = (const float*)d_in[21];
  const float* wr1     = (const float*)d_in[22];
  const float* br1     = (const float*)d_in[23];
  const float* wr2     = (const float*)d_in[24];
  const float* br2     = (const float*)d_in[25];
  float* out = (float*)d_out;

  char* W = (char*)d_ws;
  // persistent transposed bf16 weights [0,100MB)
  u16* wt_lq  = (u16*)(W + (size_t)0  * MB_);
  u16* wt_lkv = (u16*)(W + (size_t)4  * MB_);
  u16* wt_q   = (u16*)(W + (size_t)6  * MB_);
  u16* wt_qr  = (u16*)(W + (size_t)10 * MB_);
  u16* wt_k   = (u16*)(W + (size_t)12 * MB_);
  u16* wt_kr  = (u16*)(W + (size_t)14 * MB_);
  u16* wt_v   = (u16*)(W + (size_t)18 * MB_);
  u16* wt_o   = (u16*)(W + (size_t)20 * MB_);
  u16* wt_s1  = (u16*)(W + (size_t)28 * MB_);
  u16* wt_s2  = (u16*)(W + (size_t)32 * MB_);
  u16* wt_r1  = (u16*)(W + (size_t)36 * MB_);
  u16* wt_r2  = (u16*)(W + (size_t)68 * MB_);
  // phase A activations
  u16* h_bf   = (u16*)(W + (size_t)100 * MB_);
  u16* cq_bf  = (u16*)(W + (size_t)108 * MB_);
  u16* ckv_bf = (u16*)(W + (size_t)112 * MB_);
  u16* qbuf   = (u16*)(W + (size_t)114 * MB_);
  u16* qrbuf  = (u16*)(W + (size_t)122 * MB_);
  u16* kbuf   = (u16*)(W + (size_t)126 * MB_);
  u16* krbuf  = (u16*)(W + (size_t)134 * MB_);
  u16* vbuf_t = (u16*)(W + (size_t)138 * MB_);   // [2048 dv][2048 tok]
  u16* obuf   = (u16*)(W + (size_t)146 * MB_);
  // phase B activations (alias dead phase-A buffers)
  float* x2   = (float*)(W + (size_t)100 * MB_);
  float* hn   = (float*)(W + (size_t)116 * MB_);
  u16* hn_bf  = (u16*)(W + (size_t)132 * MB_);
  u16* s1b    = (u16*)(W + (size_t)140 * MB_);
  float* shb  = (float*)(W + (size_t)144 * MB_);
  u16* midb   = (u16*)(W + (size_t)160 * MB_);
  u16* oute   = (u16*)(W + (size_t)168 * MB_);
  int* ip          = (int*)(W + (size_t)184 * MB_);
  int* counts      = ip;
  int* bases       = ip + 8;
  int* topk_idx    = ip + 16;
  int* pos         = ip + 16 + 4096;
  int* token_entry = ip + 16 + 8192;
  int* entry_token = ip + 16 + 12288;
  float* topk_w    = (float*)(ip + 16 + 16384);

  // 0. weight transpose+cast (fp32 [R][C] -> bf16 [C][R])
  tcast_k<<<dim3(32, 64), 256, 0, stream>>>(w_lq,  wt_lq,  2048, 1024);
  tcast_k<<<dim3(16, 64), 256, 0, stream>>>(w_lkv, wt_lkv, 2048, 512);
  tcast_k<<<dim3(64, 32), 256, 0, stream>>>(w_q,   wt_q,   1024, 2048);
  tcast_k<<<dim3(32, 32), 256, 0, stream>>>(w_qr,  wt_qr,  1024, 1024);
  tcast_k<<<dim3(64, 16), 256, 0, stream>>>(w_k,   wt_k,   512,  2048);
  tcast_k<<<dim3(32, 64), 256, 0, stream>>>(w_kr,  wt_kr,  2048, 1024);
  tcast_k<<<dim3(64, 16), 256, 0, stream>>>(w_v,   wt_v,   512,  2048);
  tcast_k<<<dim3(64, 64), 256, 0, stream>>>(w_o,   wt_o,   2048, 2048);
  tcast_k<<<dim3(32, 64), 256, 0, stream>>>(ws1,   wt_s1,  2048, 1024);
  tcast_k<<<dim3(64, 32), 256, 0, stream>>>(ws2,   wt_s2,  1024, 2048);
  tcast_k<<<dim3(32, 64, 8), 256, 0, stream>>>(wr1, wt_r1, 2048, 1024);
  tcast_k<<<dim3(64, 32, 8), 256, 0, stream>>>(wr2, wt_r2, 1024, 2048);

  // 1. h = rms(x, w_norm1) -> bf16
  rmsb_k<<<TT, 256, 0, stream>>>(x, w_norm1, h_bf);
  // 2-3. cq, ckv
  bgemm_k<0, false, false, 1><<<dim3(8, 16), 256, 0, stream>>>(h_bf, 2048, wt_lq, 2048, cq_bf, 1024, 2048, nullptr, nullptr, 0);
  bgemm_k<0, false, false, 1><<<dim3(4, 16), 256, 0, stream>>>(h_bf, 2048, wt_lkv, 2048, ckv_bf, 512, 2048, nullptr, nullptr, 0);
  // 4-8. q, qr, k, kr, v (v stored transposed)
  bgemm_k<0, false, false, 1><<<dim3(16, 16), 256, 0, stream>>>(cq_bf, 1024, wt_q, 1024, qbuf, 2048, 1024, nullptr, nullptr, 0);
  bgemm_k<0, true,  false, 1><<<dim3(8, 16), 256, 0, stream>>>(cq_bf, 1024, wt_qr, 1024, qrbuf, 1024, 1024, b_qr, nullptr, 0);
  bgemm_k<0, false, false, 1><<<dim3(16, 16), 256, 0, stream>>>(ckv_bf, 512, wt_k, 512, kbuf, 2048, 512, nullptr, nullptr, 0);
  bgemm_k<0, true,  false, 1><<<dim3(8, 16), 256, 0, stream>>>(h_bf, 2048, wt_kr, 2048, krbuf, 1024, 2048, b_kr, nullptr, 0);
  bgemm_k<0, false, false, 2><<<dim3(16, 16), 256, 0, stream>>>(ckv_bf, 512, wt_v, 512, vbuf_t, 2048, 512, nullptr, nullptr, 0);
  // 9. RoPE
  ropeb_k<<<4096, 256, 0, stream>>>(qrbuf, fc, fs);
  ropeb_k<<<4096, 256, 0, stream>>>(krbuf, fc, fs);
  // 10. attention
  attnb_k<<<dim3(16, NH, 2), 256, 0, stream>>>(qbuf, qrbuf, kbuf, krbuf, vbuf_t, obuf);
  // 11. x2 = x + o @ w_o + b_o
  bgemm_k<0, true, true, 0><<<dim3(16, 16), 256, 0, stream>>>(obuf, 2048, wt_o, 2048, x2, 2048, 2048, b_o, x, 2048);
  // 12. hn = rms(rms(x2))
  rms2_k<<<TT, 256, 0, stream>>>(x2, w_norm2, w_moe, hn, hn_bf);
  // 13-14. shared FFN
  bgemm_k<0, true, false, 1><<<dim3(8, 16), 256, 0, stream>>>(hn_bf, 2048, wt_s1, 2048, s1b, 1024, 2048, bs1, nullptr, 0);
  bgemm_k<1, true, false, 0><<<dim3(16, 16), 256, 0, stream>>>(s1b, 1024, wt_s2, 1024, shb, 2048, 1024, bs2, nullptr, 0);
  // 15-16. router + scatter
  hipMemsetAsync(counts, 0, NE * sizeof(int), stream);
  router_k<<<TT, 256, 0, stream>>>(hn, cent, topk_idx, topk_w, pos, counts);
  scatter_k<<<1, 256, 0, stream>>>(topk_idx, pos, counts, bases, entry_token, token_entry);
  // 17-18. grouped expert GEMMs
  bgemm_grp_k<true, 0><<<dim3(8, 32, NE), 256, 0, stream>>>(hn_bf, 2048, wt_r1, 2048, 1024, midb, br1, counts, bases, entry_token);
  bgemm_grp_k<false, 1><<<dim3(16, 32, NE), 256, 0, stream>>>(midb, 1024, wt_r2, 1024, 2048, oute, br2, counts, bases, nullptr);
  // 19. combine
  combine_k<<<4096, 256, 0, stream>>>(x2, hn, shb, oute, token_entry, topk_w, out);
}

// Round 3
// 847.940 us; speedup vs baseline: 3.4136x; 1.0673x over previous
//
#include <hip/hip_runtime.h>
#include <math.h>

// B=2,S=1024,D=2048,H=16,HD=128,ROT=64,LQ=1024,LKV=512,ED=1024,E=8,TOPK=2
#define TT   2048
#define DM   2048
#define SEQ  1024
#define NH   16
#define NE   8
#define MB_  (1024*1024)
#define ATT_SCALE 0.07216878364870322f   // 1/sqrt(192)

typedef unsigned short u16;
typedef __attribute__((ext_vector_type(8))) short s8v;   // 8 x bf16 (4 VGPR)
typedef __attribute__((ext_vector_type(4))) float f4v;   // MFMA acc

__device__ __forceinline__ u16 f2bf(float f) {
  unsigned u = __builtin_bit_cast(unsigned, f);
  unsigned r = (u + 0x7fffu + ((u >> 16) & 1u)) >> 16;   // RNE
  return (u16)r;
}
__device__ __forceinline__ float bf2f(u16 h) {
  return __builtin_bit_cast(float, (unsigned)h << 16);
}
__device__ __forceinline__ float gelu_f(float x) {
  return 0.5f * x * (1.0f + erff(x * 0.7071067811865476f));
}
__device__ __forceinline__ f4v mfma16(s8v a, s8v b, f4v c) {
  return __builtin_amdgcn_mfma_f32_16x16x32_bf16(a, b, c, 0, 0, 0);
}
// async global->LDS, 16B per lane; LDS dest = wave-uniform base + lane*16
__device__ __forceinline__ void gload16(const u16* g, u16* l) {
  __builtin_amdgcn_global_load_lds(
      (const __attribute__((address_space(1))) unsigned*)g,
      (__attribute__((address_space(3))) unsigned*)l, 16, 0, 0);
}

// ---------------- transpose + cast: src fp32 [R][C] -> dst bf16 [C][R] ----------------
__global__ __launch_bounds__(256) void tcast_k(const float* __restrict__ src,
                                               u16* __restrict__ dst, int R, int C) {
  __shared__ float tile[32][33];
  const size_t bofs = (size_t)blockIdx.z * R * C;
  src += bofs; dst += bofs;
  const int r0 = blockIdx.y * 32, c0 = blockIdx.x * 32;
  const int t = threadIdx.x;
  const int tr = t >> 3, tc4 = (t & 7) * 4;
  float4 v = *(const float4*)&src[(size_t)(r0 + tr) * C + c0 + tc4];
  tile[tr][tc4 + 0] = v.x; tile[tr][tc4 + 1] = v.y;
  tile[tr][tc4 + 2] = v.z; tile[tr][tc4 + 3] = v.w;
  __syncthreads();
  ushort4 o;
  o.x = f2bf(tile[tc4 + 0][tr]);
  o.y = f2bf(tile[tc4 + 1][tr]);
  o.z = f2bf(tile[tc4 + 2][tr]);
  o.w = f2bf(tile[tc4 + 3][tr]);
  *(ushort4*)&dst[(size_t)(c0 + tr) * R + r0 + tc4] = o;
}

// ---------------- concat bias fill ----------------
__global__ __launch_bounds__(256) void biasfill_k(float* __restrict__ bh,
                                                  float* __restrict__ bq,
                                                  const float* __restrict__ bkr,
                                                  const float* __restrict__ bqr) {
  const int i = blockIdx.x * 256 + threadIdx.x;   // 0..3071
  if (i < 2560) bh[i] = (i >= 1536) ? bkr[i - 1536] : 0.f;
  bq[i] = (i >= 2048) ? bqr[i - 2048] : 0.f;
}

__device__ __forceinline__ float block_sum(float v, float* red) {
#pragma unroll
  for (int m = 32; m; m >>= 1) v += __shfl_xor(v, m);
  __syncthreads();
  if ((threadIdx.x & 63) == 0) red[threadIdx.x >> 6] = v;
  __syncthreads();
  return red[0] + red[1] + red[2] + red[3];
}

// ---------------- RMSNorm -> bf16 ----------------
__global__ __launch_bounds__(256) void rmsb_k(const float* __restrict__ x,
                                              const float* __restrict__ w,
                                              u16* __restrict__ out) {
  __shared__ float red[4];
  const int t = blockIdx.x, tid = threadIdx.x;
  const float* xr = x + (size_t)t * DM;
  float4 v0 = *(const float4*)&xr[tid * 4];
  float4 v1 = *(const float4*)&xr[1024 + tid * 4];
  float ss = v0.x*v0.x + v0.y*v0.y + v0.z*v0.z + v0.w*v0.w
           + v1.x*v1.x + v1.y*v1.y + v1.z*v1.z + v1.w*v1.w;
  float s = block_sum(ss, red);
  float r = rsqrtf(s * (1.0f / DM) + 1e-6f);
  float4 w0 = *(const float4*)&w[tid * 4];
  float4 w1 = *(const float4*)&w[1024 + tid * 4];
  u16* orow = out + (size_t)t * DM;
  ushort4 o0, o1;
  o0.x = f2bf(v0.x*r*w0.x); o0.y = f2bf(v0.y*r*w0.y);
  o0.z = f2bf(v0.z*r*w0.z); o0.w = f2bf(v0.w*r*w0.w);
  o1.x = f2bf(v1.x*r*w1.x); o1.y = f2bf(v1.y*r*w1.y);
  o1.z = f2bf(v1.z*r*w1.z); o1.w = f2bf(v1.w*r*w1.w);
  *(ushort4*)&orow[tid * 4] = o0;
  *(ushort4*)&orow[1024 + tid * 4] = o1;
}

// double RMS -> fp32 + bf16
__global__ __launch_bounds__(256) void rms2_k(const float* __restrict__ x,
                                              const float* __restrict__ w2,
                                              const float* __restrict__ wm,
                                              float* __restrict__ outf,
                                              u16* __restrict__ outb) {
  __shared__ float red[4];
  const int t = blockIdx.x, tid = threadIdx.x;
  const float* xr = x + (size_t)t * DM;
  float4 v0 = *(const float4*)&xr[tid * 4];
  float4 v1 = *(const float4*)&xr[1024 + tid * 4];
  float ss = v0.x*v0.x + v0.y*v0.y + v0.z*v0.z + v0.w*v0.w
           + v1.x*v1.x + v1.y*v1.y + v1.z*v1.z + v1.w*v1.w;
  float s1 = block_sum(ss, red);
  float r1 = rsqrtf(s1 * (1.0f / DM) + 1e-6f);
  float4 a0 = *(const float4*)&w2[tid * 4];
  float4 a1 = *(const float4*)&w2[1024 + tid * 4];
  float4 y0 = make_float4(v0.x*r1*a0.x, v0.y*r1*a0.y, v0.z*r1*a0.z, v0.w*r1*a0.w);
  float4 y1 = make_float4(v1.x*r1*a1.x, v1.y*r1*a1.y, v1.z*r1*a1.z, v1.w*r1*a1.w);
  float ss2 = y0.x*y0.x + y0.y*y0.y + y0.z*y0.z + y0.w*y0.w
            + y1.x*y1.x + y1.y*y1.y + y1.z*y1.z + y1.w*y1.w;
  float s2 = block_sum(ss2, red);
  float r2 = rsqrtf(s2 * (1.0f / DM) + 1e-6f);
  float4 b0 = *(const float4*)&wm[tid * 4];
  float4 b1 = *(const float4*)&wm[1024 + tid * 4];
  float4 z0 = make_float4(y0.x*r2*b0.x, y0.y*r2*b0.y, y0.z*r2*b0.z, y0.w*r2*b0.w);
  float4 z1 = make_float4(y1.x*r2*b1.x, y1.y*r2*b1.y, y1.z*r2*b1.z, y1.w*r2*b1.w);
  float* orow = outf + (size_t)t * DM;
  *(float4*)&orow[tid * 4] = z0;
  *(float4*)&orow[1024 + tid * 4] = z1;
  u16* brow = outb + (size_t)t * DM;
  ushort4 o0, o1;
  o0.x = f2bf(z0.x); o0.y = f2bf(z0.y); o0.z = f2bf(z0.z); o0.w = f2bf(z0.w);
  o1.x = f2bf(z1.x); o1.y = f2bf(z1.y); o1.z = f2bf(z1.z); o1.w = f2bf(z1.w);
  *(ushort4*)&brow[tid * 4] = o0;
  *(ushort4*)&brow[1024 + tid * 4] = o1;
}

// ---------------- bf16 MFMA GEMM, global_load_lds staging (m97 recipe) ----------------
// C(MxN) = A(MxK) * Bt(NxK)^T. 128x128 tile, BK=64, 4 waves, linear LDS [128][64].
// OUT: 0=f32, 1=bf16, 3=split (col<nsplit -> bf16 C; col>=nsplit -> bf16 transposed C2)
template <int ACT, bool BIAS, bool RES, int OUT>
__global__ __launch_bounds__(256) void bgemm_k(const u16* __restrict__ A, int lda,
                                               const u16* __restrict__ Bt, int ldb,
                                               void* __restrict__ C, int ldc, int K,
                                               const float* __restrict__ bias,
                                               const float* __restrict__ res, int ldr,
                                               void* __restrict__ C2, int ldc2, int nsplit) {
  __shared__ u16 As[128 * 64];
  __shared__ u16 Bs[128 * 64];
  const int tid = threadIdx.x;
  const int lane = tid & 63, w = tid >> 6;
  const int wr = w >> 1, wc = w & 1;
  const int l15 = lane & 15, l4 = lane >> 4;
  const int bm = blockIdx.y * 128, bn = blockIdx.x * 128;
  const int lrow = lane >> 3, lcol = (lane & 7) * 8;
  const u16* Abase = A + (size_t)(bm + w * 32 + lrow) * lda + lcol;
  const u16* Bbase = Bt + (size_t)(bn + w * 32 + lrow) * ldb + lcol;
  u16* AsW = As + (w * 32) * 64;
  u16* BsW = Bs + (w * 32) * 64;
  f4v acc[4][4] = {};
  for (int k0 = 0; k0 < K; k0 += 64) {
    __syncthreads();
#pragma unroll
    for (int j = 0; j < 4; ++j) {
      gload16(Abase + (size_t)j * 8 * lda + k0, AsW + j * 8 * 64);
      gload16(Bbase + (size_t)j * 8 * ldb + k0, BsW + j * 8 * 64);
    }
    __syncthreads();
#pragma unroll
    for (int kk = 0; kk < 2; ++kk) {
      s8v af[4], bfr[4];
#pragma unroll
      for (int m = 0; m < 4; ++m)
        af[m] = *(const s8v*)(As + (wr * 64 + m * 16 + l15) * 64 + kk * 32 + l4 * 8);
#pragma unroll
      for (int n = 0; n < 4; ++n)
        bfr[n] = *(const s8v*)(Bs + (wc * 64 + n * 16 + l15) * 64 + kk * 32 + l4 * 8);
#pragma unroll
      for (int m = 0; m < 4; ++m)
#pragma unroll
        for (int n = 0; n < 4; ++n)
          acc[m][n] = mfma16(af[m], bfr[n], acc[m][n]);
    }
  }
#pragma unroll
  for (int m = 0; m < 4; ++m) {
    const int row0 = bm + wr * 64 + m * 16 + l4 * 4;
#pragma unroll
    for (int n = 0; n < 4; ++n) {
      const int col = bn + wc * 64 + n * 16 + l15;
      f4v v = acc[m][n];
      float bv = BIAS ? bias[col] : 0.0f;
      if (OUT == 3 && col >= nsplit) {
        ushort4 o;
        o.x = f2bf(v[0] + bv); o.y = f2bf(v[1] + bv);
        o.z = f2bf(v[2] + bv); o.w = f2bf(v[3] + bv);
        *(ushort4*)((u16*)C2 + (size_t)(col - nsplit) * ldc2 + row0) = o;
      } else {
#pragma unroll
        for (int r = 0; r < 4; ++r) {
          float o = v[r] + bv;
          if (RES) o += res[(size_t)(row0 + r) * ldr + col];
          if (ACT == 1) o = gelu_f(o);
          if (OUT == 0) ((float*)C)[(size_t)(row0 + r) * ldc + col] = o;
          else          ((u16*)C)[(size_t)(row0 + r) * ldc + col] = f2bf(o);
        }
      }
    }
  }
}

// ---------------- grouped expert bf16 GEMM (top-2 sparse), gload_lds staging --------
template <bool GATHER, int ACT>
__global__ __launch_bounds__(256) void bgemm_grp_k(const u16* __restrict__ A, int lda,
                                                   const u16* __restrict__ BtAll, int K, int N,
                                                   u16* __restrict__ C,
                                                   const float* __restrict__ biasAll,
                                                   const int* __restrict__ counts,
                                                   const int* __restrict__ bases,
                                                   const int* __restrict__ entry_token) {
  const int e = blockIdx.z;
  const int cnt = counts[e];
  const int m0 = blockIdx.y * 128;
  if (m0 >= cnt) return;
  const int base = bases[e];
  const u16* Bt = BtAll + (size_t)e * K * N;
  const float* bias = biasAll + (size_t)e * N;
  __shared__ u16 As[128 * 64];
  __shared__ u16 Bs[128 * 64];
  const int tid = threadIdx.x;
  const int lane = tid & 63, w = tid >> 6;
  const int wr = w >> 1, wc = w & 1;
  const int l15 = lane & 15, l4 = lane >> 4;
  const int bn = blockIdx.x * 128;
  const int lrow = lane >> 3, lcol = (lane & 7) * 8;
  int aro[4];
#pragma unroll
  for (int j = 0; j < 4; ++j) {
    int rr = m0 + w * 32 + j * 8 + lrow;
    if (rr >= cnt) rr = cnt - 1;
    aro[j] = GATHER ? entry_token[base + rr] : (base + rr);
  }
  const u16* Bbase = Bt + (size_t)(bn + w * 32 + lrow) * K + lcol;
  u16* AsW = As + (w * 32) * 64;
  u16* BsW = Bs + (w * 32) * 64;
  f4v acc[4][4] = {};
  for (int k0 = 0; k0 < K; k0 += 64) {
    __syncthreads();
#pragma unroll
    for (int j = 0; j < 4; ++j) {
      gload16(A + (size_t)aro[j] * lda + k0 + lcol, AsW + j * 8 * 64);
      gload16(Bbase + (size_t)j * 8 * K + k0, BsW + j * 8 * 64);
    }
    __syncthreads();
#pragma unroll
    for (int kk = 0; kk < 2; ++kk) {
      s8v af[4], bfr[4];
#pragma unroll
      for (int m = 0; m < 4; ++m)
        af[m] = *(const s8v*)(As + (wr * 64 + m * 16 + l15) * 64 + kk * 32 + l4 * 8);
#pragma unroll
      for (int n = 0; n < 4; ++n)
        bfr[n] = *(const s8v*)(Bs + (wc * 64 + n * 16 + l15) * 64 + kk * 32 + l4 * 8);
#pragma unroll
      for (int m = 0; m < 4; ++m)
#pragma unroll
        for (int n = 0; n < 4; ++n)
          acc[m][n] = mfma16(af[m], bfr[n], acc[m][n]);
    }
  }
#pragma unroll
  for (int m = 0; m < 4; ++m) {
    const int rl0 = m0 + wr * 64 + m * 16 + l4 * 4;
#pragma unroll
    for (int n = 0; n < 4; ++n) {
      const int col = bn + wc * 64 + n * 16 + l15;
      f4v v = acc[m][n];
      float bv = bias[col];
#pragma unroll
      for (int r = 0; r < 4; ++r) {
        const int rl = rl0 + r;
        if (rl < cnt) {
          float o = v[r] + bv;
          if (ACT == 1) o = gelu_f(o);
          C[(size_t)(base + rl) * N + col] = f2bf(o);
        }
      }
    }
  }
}

// ---------------- RoPE in place on bf16 (strided rows) ----------------
__global__ __launch_bounds__(256) void ropeb_k(u16* __restrict__ buf, int ldb,
                                               const float* __restrict__ cosb,
                                               const float* __restrict__ sinb) {
  const int i = blockIdx.x * 256 + threadIdx.x;   // pair index over TT*NH*32
  const int t = i >> 9;
  const int rem = i & 511;
  const int hh2 = rem >> 5, p = rem & 31;
  const int s = t & (SEQ - 1);
  const float c = cosb[s * 32 + p], sn = sinb[s * 32 + p];
  unsigned* ptr = (unsigned*)(buf + (size_t)t * ldb + hh2 * 64 + p * 2);
  unsigned vv = *ptr;
  float x0 = bf2f((u16)(vv & 0xffffu)), x1 = bf2f((u16)(vv >> 16));
  float y0 = x0 * c - x1 * sn, y1 = x0 * sn + x1 * c;
  *ptr = (unsigned)f2bf(y0) | ((unsigned)f2bf(y1) << 16);
}

// ---------------- bf16 MFMA flash attention ----------------
__global__ __launch_bounds__(256) void attnb_k(const u16* __restrict__ qb, int ldq,
                                               const u16* __restrict__ qrb, int ldqr,
                                               const u16* __restrict__ kb, int ldk,
                                               const u16* __restrict__ krb, int ldkr,
                                               const u16* __restrict__ vt,
                                               u16* __restrict__ ob) {
  __shared__ u16 Ks[32 * 200];
  __shared__ u16 Vs[128 * 40];
  __shared__ u16 Ps[4][16 * 40];
  const int tid = threadIdx.x, lane = tid & 63, w = tid >> 6;
  const int l15 = lane & 15, l4 = lane >> 4;
  const int hh = blockIdx.y, bb = blockIdx.z;
  const int tbase = bb * SEQ;
  const int q0 = blockIdx.x * 64 + w * 16;
  const int qtok = tbase + q0 + l15;
  s8v aq[6];
#pragma unroll
  for (int kc = 0; kc < 4; ++kc)
    aq[kc] = *(const s8v*)(qb + (size_t)qtok * ldq + hh * 128 + kc * 32 + l4 * 8);
#pragma unroll
  for (int kc = 0; kc < 2; ++kc)
    aq[4 + kc] = *(const s8v*)(qrb + (size_t)qtok * ldqr + hh * 64 + kc * 32 + l4 * 8);
  f4v o[8] = {};
  float m_run[4] = {-1e30f, -1e30f, -1e30f, -1e30f};
  float l_run[4] = {0.f, 0.f, 0.f, 0.f};
  for (int kt = 0; kt < SEQ / 32; ++kt) {
    __syncthreads();
#pragma unroll
    for (int i = 0; i < 3; ++i) {                 // stage K-concat: 32 x 192
      int q = i * 256 + tid;
      int row = q / 24, c = q % 24;
      int tok = tbase + kt * 32 + row;
      s8v v;
      if (c < 16) v = *(const s8v*)(kb  + (size_t)tok * ldk + hh * 128 + c * 8);
      else        v = *(const s8v*)(krb + (size_t)tok * ldkr + hh * 64 + (c - 16) * 8);
      *(s8v*)(Ks + row * 200 + c * 8) = v;
    }
#pragma unroll
    for (int i = 0; i < 2; ++i) {                 // stage V^T: 128 x 32
      int q = i * 256 + tid;
      int row = q >> 2, c = q & 3;
      s8v v = *(const s8v*)(vt + (size_t)(hh * 128 + row) * 2048 + tbase + kt * 32 + c * 8);
      *(s8v*)(Vs + row * 40 + c * 8) = v;
    }
    __syncthreads();
    f4v s0 = {}, s1 = {};
#pragma unroll
    for (int kc = 0; kc < 6; ++kc) {              // S = Q K^T (two 16-col tiles)
      s8v bk0 = *(const s8v*)(Ks + l15 * 200 + kc * 32 + l4 * 8);
      s8v bk1 = *(const s8v*)(Ks + (16 + l15) * 200 + kc * 32 + l4 * 8);
      s0 = mfma16(aq[kc], bk0, s0);
      s1 = mfma16(aq[kc], bk1, s1);
    }
    float scf[4];
#pragma unroll
    for (int r = 0; r < 4; ++r) {                 // online softmax, rows (l4*4+r)
      float a = s0[r] * ATT_SCALE, b = s1[r] * ATT_SCALE;
      float mt = fmaxf(a, b);
#pragma unroll
      for (int msk = 1; msk < 16; msk <<= 1) mt = fmaxf(mt, __shfl_xor(mt, msk));
      float mn = fmaxf(m_run[r], mt);
      float p0 = __expf(a - mn), p1 = __expf(b - mn);
      float rs = p0 + p1;
#pragma unroll
      for (int msk = 1; msk < 16; msk <<= 1) rs += __shfl_xor(rs, msk);
      float sc = __expf(m_run[r] - mn);
      l_run[r] = l_run[r] * sc + rs;
      m_run[r] = mn;
      scf[r] = sc;
      int rq = l4 * 4 + r;
      Ps[w][rq * 40 + l15] = f2bf(p0);
      Ps[w][rq * 40 + 16 + l15] = f2bf(p1);
    }
#pragma unroll
    for (int dt = 0; dt < 8; ++dt) {
      o[dt][0] *= scf[0]; o[dt][1] *= scf[1];
      o[dt][2] *= scf[2]; o[dt][3] *= scf[3];
    }
    s8v pa = *(const s8v*)(&Ps[w][l15 * 40 + l4 * 8]);
#pragma unroll
    for (int dt = 0; dt < 8; ++dt) {              // O += P V
      s8v bv = *(const s8v*)(Vs + (dt * 16 + l15) * 40 + l4 * 8);
      o[dt] = mfma16(pa, bv, o[dt]);
    }
  }
  float linv[4];
#pragma unroll
  for (int r = 0; r < 4; ++r) linv[r] = 1.0f / l_run[r];
#pragma unroll
  for (int dt = 0; dt < 8; ++dt)
#pragma unroll
    for (int r = 0; r < 4; ++r)
      ob[(size_t)(tbase + q0 + l4 * 4 + r) * 2048 + hh * 128 + dt * 16 + l15] =
          f2bf(o[dt][r] * linv[r]);
}

// ---------------- router ----------------
__global__ __launch_bounds__(256) void router_k(const float* __restrict__ hn,
                                                const float* __restrict__ cent,
                                                int* __restrict__ topk_idx,
                                                float* __restrict__ topk_w,
                                                int* __restrict__ pos,
                                                int* __restrict__ counts) {
  const int t = blockIdx.x, tid = threadIdx.x;
  float p[NE] = {};
  const float* xr = hn + (size_t)t * DM;
  for (int d = tid * 4; d < DM; d += 1024) {
    float4 xv = *(const float4*)&xr[d];
#pragma unroll
    for (int e = 0; e < NE; ++e) {
      float4 cv = *(const float4*)&cent[e * DM + d];
      p[e] += xv.x * cv.x + xv.y * cv.y + xv.z * cv.z + xv.w * cv.w;
    }
  }
  __shared__ float wred[NE][4];
#pragma unroll
  for (int e = 0; e < NE; ++e) {
    float v = p[e];
#pragma unroll
    for (int m = 32; m; m >>= 1) v += __shfl_xor(v, m);
    if ((tid & 63) == 0) wred[e][tid >> 6] = v;
  }
  __syncthreads();
  if (tid == 0) {
    float lg[NE], mx = -3.0e38f;
    for (int e = 0; e < NE; ++e) {
      lg[e] = wred[e][0] + wred[e][1] + wred[e][2] + wred[e][3];
      mx = fmaxf(mx, lg[e]);
    }
    float pe[NE], sum = 0.f;
    for (int e = 0; e < NE; ++e) { pe[e] = expf(lg[e] - mx); sum += pe[e]; }
    const float inv = 1.f / sum;
    int i0 = 0; float v0 = -1.f;
    for (int e = 0; e < NE; ++e) { float a = pe[e] * inv; if (a > v0) { v0 = a; i0 = e; } }
    int i1 = 0; float v1 = -1.f;
    for (int e = 0; e < NE; ++e) { if (e == i0) continue; float a = pe[e] * inv; if (a > v1) { v1 = a; i1 = e; } }
    topk_idx[t * 2 + 0] = i0;
    topk_idx[t * 2 + 1] = i1;
    topk_w[t * 2 + 0] = v0;
    topk_w[t * 2 + 1] = v1;
    pos[t * 2 + 0] = atomicAdd(&counts[i0], 1);
    pos[t * 2 + 1] = atomicAdd(&counts[i1], 1);
  }
}

// ---------------- prefix + scatter ----------------
__global__ __launch_bounds__(256) void scatter_k(const int* __restrict__ topk_idx,
                                                 const int* __restrict__ pos,
                                                 const int* __restrict__ counts,
                                                 int* __restrict__ bases,
                                                 int* __restrict__ entry_token,
                                                 int* __restrict__ token_entry) {
  __shared__ int sb[NE];
  const int tid = threadIdx.x;
  if (tid == 0) {
    int acc = 0;
    for (int e = 0; e < NE; ++e) { sb[e] = acc; bases[e] = acc; acc += counts[e]; }
  }
  __syncthreads();
  for (int i = tid; i < TT * 2; i += 256) {
    const int e = topk_idx[i];
    const int entry = sb[e] + pos[i];
    entry_token[entry] = i >> 1;
    token_entry[i] = entry;
  }
}

// ---------------- combine ----------------
__global__ __launch_bounds__(256) void combine_k(const float* __restrict__ x2,
                                                 const float* __restrict__ hn,
                                                 const float* __restrict__ sh,
                                                 const u16* __restrict__ oute,
                                                 const int* __restrict__ token_entry,
                                                 const float* __restrict__ topk_w,
                                                 float* __restrict__ out) {
  const int i = blockIdx.x * 256 + threadIdx.x;
  const int t = i >> 9;
  const int c = (i & 511) * 4;
  const int e0 = token_entry[t * 2 + 0], e1 = token_entry[t * 2 + 1];
  const float w0 = topk_w[t * 2 + 0], w1 = topk_w[t * 2 + 1];
  float4 a = *(const float4*)&x2[(size_t)t * DM + c];
  float4 b = *(const float4*)&hn[(size_t)t * DM + c];
  float4 s = *(const float4*)&sh[(size_t)t * DM + c];
  ushort4 u0 = *(const ushort4*)&oute[(size_t)e0 * DM + c];
  ushort4 u1 = *(const ushort4*)&oute[(size_t)e1 * DM + c];
  *(float4*)&out[(size_t)t * DM + c] =
      make_float4(a.x + b.x + s.x + w0 * bf2f(u0.x) + w1 * bf2f(u1.x),
                  a.y + b.y + s.y + w0 * bf2f(u0.y) + w1 * bf2f(u1.y),
                  a.z + b.z + s.z + w0 * bf2f(u0.z) + w1 * bf2f(u1.z),
                  a.w + b.w + s.w + w0 * bf2f(u0.w) + w1 * bf2f(u1.w));
}

// ---------------- host ----------------
extern "C" void kernel_launch(void* const* d_in, const int* in_sizes, int n_in,
                              void* d_out, int out_size, void* d_ws, size_t ws_size,
                              hipStream_t stream) {
  (void)in_sizes; (void)n_in; (void)out_size; (void)ws_size;
  const float* x       = (const float*)d_in[0];
  const float* fc      = (const float*)d_in[1];
  const float* fs      = (const float*)d_in[2];
  const float* w_norm1 = (const float*)d_in[3];
  const float* w_lq    = (const float*)d_in[4];
  const float* w_lkv   = (const float*)d_in[5];
  const float* w_q     = (const float*)d_in[6];
  const float* w_k     = (const float*)d_in[7];
  const float* w_v     = (const float*)d_in[8];
  const float* w_qr    = (const float*)d_in[9];
  const float* b_qr    = (const float*)d_in[10];
  const float* w_kr    = (const float*)d_in[11];
  const float* b_kr    = (const float*)d_in[12];
  const float* w_o     = (const float*)d_in[13];
  const float* b_o     = (const float*)d_in[14];
  const float* w_norm2 = (const float*)d_in[15];
  const float* w_moe   = (const float*)d_in[16];
  const float* cent    = (const float*)d_in[17];
  const float* ws1     = (const float*)d_in[18];
  const float* bs1     = (const float*)d_in[19];
  const float* ws2     = (const float*)d_in[20];
  const float* bs2     = (const float*)d_in[21];
  const float* wr1     = (const float*)d_in[22];
  const float* br1     = (const float*)d_in[23];
  const float* wr2     = (const float*)d_in[24];
  const float* br2     = (const float*)d_in[25];
  float* out = (float*)d_out;

  char* W = (char*)d_ws;
  // persistent transposed bf16 weights [0,100MB)
  u16* wt_h   = (u16*)(W + (size_t)0  * MB_);   // [2560][2048]: lq|lkv|kr
  u16* wt_qqr = (u16*)(W + (size_t)10 * MB_);   // [3072][1024]: q|qr
  u16* wt_kv  = (u16*)(W + (size_t)16 * MB_);   // [4096][512]:  k|v
  u16* wt_o   = (u16*)(W + (size_t)20 * MB_);   // [2048][2048]
  u16* wt_s1  = (u16*)(W + (size_t)28 * MB_);   // [1024][2048]
  u16* wt_s2  = (u16*)(W + (size_t)32 * MB_);   // [2048][1024]
  u16* wt_r1  = (u16*)(W + (size_t)36 * MB_);   // 8x[1024][2048]
  u16* wt_r2  = (u16*)(W + (size_t)68 * MB_);   // 8x[2048][1024]
  // phase A activations
  u16* h_bf   = (u16*)(W + (size_t)100 * MB_);  // [2048][2048]
  u16* hp     = (u16*)(W + (size_t)108 * MB_);  // [2048][2560]: cq|ckv|kr
  u16* qp     = (u16*)(W + (size_t)118 * MB_);  // [2048][3072]: q|qr
  u16* kbuf   = (u16*)(W + (size_t)130 * MB_);  // [2048][2048]
  u16* vbuf_t = (u16*)(W + (size_t)138 * MB_);  // [2048 dv][2048 tok]
  u16* obuf   = (u16*)(W + (size_t)146 * MB_);  // [2048][2048]
  // phase B activations (alias dead phase-A buffers)
  float* x2   = (float*)(W + (size_t)100 * MB_);
  float* hn   = (float*)(W + (size_t)116 * MB_);
  u16* hn_bf  = (u16*)(W + (size_t)132 * MB_);
  u16* s1b    = (u16*)(W + (size_t)140 * MB_);
  float* shb  = (float*)(W + (size_t)144 * MB_);
  u16* midb   = (u16*)(W + (size_t)160 * MB_);
  u16* oute   = (u16*)(W + (size_t)168 * MB_);
  int* ip          = (int*)(W + (size_t)184 * MB_);
  int* counts      = ip;
  int* bases       = ip + 8;
  int* topk_idx    = ip + 16;
  int* pos         = ip + 16 + 4096;
  int* token_entry = ip + 16 + 8192;
  int* entry_token = ip + 16 + 12288;
  float* topk_w    = (float*)(ip + 16 + 16384);
  float* bias_h    = (float*)(ip + 16 + 20480);   // [2560]
  float* bias_q    = bias_h + 2560;               // [3072]

  // 0. weight transpose+cast into concatenated layouts
  tcast_k<<<dim3(32, 64), 256, 0, stream>>>(w_lq,  wt_h,                    2048, 1024);
  tcast_k<<<dim3(16, 64), 256, 0, stream>>>(w_lkv, wt_h + 1024 * 2048,      2048, 512);
  tcast_k<<<dim3(32, 64), 256, 0, stream>>>(w_kr,  wt_h + 1536 * 2048,      2048, 1024);
  tcast_k<<<dim3(64, 32), 256, 0, stream>>>(w_q,   wt_qqr,                  1024, 2048);
  tcast_k<<<dim3(32, 32), 256, 0, stream>>>(w_qr,  wt_qqr + 2048 * 1024,    1024, 1024);
  tcast_k<<<dim3(64, 16), 256, 0, stream>>>(w_k,   wt_kv,                   512,  2048);
  tcast_k<<<dim3(64, 16), 256, 0, stream>>>(w_v,   wt_kv + 2048 * 512,      512,  2048);
  tcast_k<<<dim3(64, 64), 256, 0, stream>>>(w_o,   wt_o,                    2048, 2048);
  tcast_k<<<dim3(32, 64), 256, 0, stream>>>(ws1,   wt_s1,                   2048, 1024);
  tcast_k<<<dim3(64, 32), 256, 0, stream>>>(ws2,   wt_s2,                   1024, 2048);
  tcast_k<<<dim3(32, 64, 8), 256, 0, stream>>>(wr1, wt_r1,                  2048, 1024);
  tcast_k<<<dim3(64, 32, 8), 256, 0, stream>>>(wr2, wt_r2,                  1024, 2048);
  biasfill_k<<<12, 256, 0, stream>>>(bias_h, bias_q, b_kr, b_qr);

  // 1. h = rms(x, w_norm1) -> bf16
  rmsb_k<<<TT, 256, 0, stream>>>(x, w_norm1, h_bf);
  // 2. fused G1: h -> [cq | ckv | kr]  (N=2560, K=2048)
  bgemm_k<0, true, false, 1><<<dim3(20, 16), 256, 0, stream>>>(
      h_bf, 2048, wt_h, 2048, hp, 2560, 2048, bias_h, nullptr, 0, nullptr, 0, 0);
  // 3. fused G2: cq -> [q | qr]  (N=3072, K=1024)
  bgemm_k<0, true, false, 1><<<dim3(24, 16), 256, 0, stream>>>(
      hp, 2560, wt_qqr, 1024, qp, 3072, 1024, bias_q, nullptr, 0, nullptr, 0, 0);
  // 4. fused G3: ckv -> [k | v^T]  (N=4096, K=512, split epilogue)
  bgemm_k<0, false, false, 3><<<dim3(32, 16), 256, 0, stream>>>(
      hp + 1024, 2560, wt_kv, 512, kbuf, 2048, 512, nullptr, nullptr, 0, vbuf_t, 2048, 2048);
  // 5. RoPE on qr (qp cols 2048+) and kr (hp cols 1536+)
  ropeb_k<<<4096, 256, 0, stream>>>(qp + 2048, 3072, fc, fs);
  ropeb_k<<<4096, 256, 0, stream>>>(hp + 1536, 2560, fc, fs);
  // 6. attention
  attnb_k<<<dim3(16, NH, 2), 256, 0, stream>>>(qp, 3072, qp + 2048, 3072,
                                               kbuf, 2048, hp + 1536, 2560, vbuf_t, obuf);
  // 7. x2 = x + o @ w_o + b_o
  bgemm_k<0, true, true, 0><<<dim3(16, 16), 256, 0, stream>>>(
      obuf, 2048, wt_o, 2048, x2, 2048, 2048, b_o, x, 2048, nullptr, 0, 0);
  // 8. hn = rms(rms(x2))
  rms2_k<<<TT, 256, 0, stream>>>(x2, w_norm2, w_moe, hn, hn_bf);
  // 9-10. shared FFN
  bgemm_k<0, true, false, 1><<<dim3(8, 16), 256, 0, stream>>>(
      hn_bf, 2048, wt_s1, 2048, s1b, 1024, 2048, bs1, nullptr, 0, nullptr, 0, 0);
  bgemm_k<1, true, false, 0><<<dim3(16, 16), 256, 0, stream>>>(
      s1b, 1024, wt_s2, 1024, shb, 2048, 1024, bs2, nullptr, 0, nullptr, 0, 0);
  // 11-12. router + scatter
  hipMemsetAsync(counts, 0, NE * sizeof(int), stream);
  router_k<<<TT, 256, 0, stream>>>(hn, cent, topk_idx, topk_w, pos, counts);
  scatter_k<<<1, 256, 0, stream>>>(topk_idx, pos, counts, bases, entry_token, token_entry);
  // 13-14. grouped expert GEMMs
  bgemm_grp_k<true, 0><<<dim3(8, 32, NE), 256, 0, stream>>>(
      hn_bf, 2048, wt_r1, 2048, 1024, midb, br1, counts, bases, entry_token);
  bgemm_grp_k<false, 1><<<dim3(16, 32, NE), 256, 0, stream>>>(
      midb, 1024, wt_r2, 1024, 2048, oute, br2, counts, bases, nullptr);
  // 15. combine
  combine_k<<<4096, 256, 0, stream>>>(x2, hn, shb, oute, token_entry, topk_w, out);
}

// Round 5
// 820.866 us; speedup vs baseline: 3.5262x; 1.0330x over previous
//
#include <hip/hip_runtime.h>
#include <math.h>

// B=2,S=1024,D=2048,H=16,HD=128,ROT=64,LQ=1024,LKV=512,ED=1024,E=8,TOPK=2
#define TT   2048
#define DM   2048
#define SEQ  1024
#define NH   16
#define NE   8
#define MB_  (1024*1024)
#define ATT_SCALE 0.07216878364870322f   // 1/sqrt(192)

typedef unsigned short u16;
typedef __attribute__((ext_vector_type(8))) short s8v;   // 8 x bf16 (4 VGPR)
typedef __attribute__((ext_vector_type(4))) float f4v;   // MFMA acc

__device__ __forceinline__ u16 f2bf(float f) {
  unsigned u = __builtin_bit_cast(unsigned, f);
  unsigned r = (u + 0x7fffu + ((u >> 16) & 1u)) >> 16;   // RNE
  return (u16)r;
}
__device__ __forceinline__ float bf2f(u16 h) {
  return __builtin_bit_cast(float, (unsigned)h << 16);
}
__device__ __forceinline__ float gelu_f(float x) {
  return 0.5f * x * (1.0f + erff(x * 0.7071067811865476f));
}
__device__ __forceinline__ f4v mfma16(s8v a, s8v b, f4v c) {
  return __builtin_amdgcn_mfma_f32_16x16x32_bf16(a, b, c, 0, 0, 0);
}
// async global->LDS, 16B per lane; LDS dest = wave-uniform base + lane*16
__device__ __forceinline__ void gload16(const u16* g, u16* l) {
  __builtin_amdgcn_global_load_lds(
      (const __attribute__((address_space(1))) unsigned*)g,
      (__attribute__((address_space(3))) unsigned*)l, 16, 0, 0);
}

// ---------------- batched transpose+cast: fp32 [z][R][C] -> bf16 [z][C][R] ----------
struct TD { const float* src; u16* dst; int R; int C; int startTile; };
struct TDs { TD d[12]; };

__global__ __launch_bounds__(256) void tcastb_k(TDs P) {
  __shared__ float tile[32][33];
  const int b = blockIdx.x;
  int i = 0;
#pragma unroll
  for (int j = 1; j < 12; ++j) if (b >= P.d[j].startTile) i = j;
  const float* src0 = P.d[i].src;
  u16* dst0 = P.d[i].dst;
  const int R = P.d[i].R, C = P.d[i].C;
  const int local = b - P.d[i].startTile;
  const int cpt = C >> 5;
  const int ty = local / cpt, tx = local - ty * cpt;
  const int r0g = ty * 32, c0 = tx * 32;
  const int z = r0g / R;
  const int r0 = r0g - z * R;
  const float* src = src0 + (size_t)z * R * C;
  u16* dst = dst0 + (size_t)z * R * C;
  const int t = threadIdx.x;
  const int tr = t >> 3, tc4 = (t & 7) * 4;
  float4 v = *(const float4*)&src[(size_t)(r0 + tr) * C + c0 + tc4];
  tile[tr][tc4 + 0] = v.x; tile[tr][tc4 + 1] = v.y;
  tile[tr][tc4 + 2] = v.z; tile[tr][tc4 + 3] = v.w;
  __syncthreads();
  ushort4 o;
  o.x = f2bf(tile[tc4 + 0][tr]);
  o.y = f2bf(tile[tc4 + 1][tr]);
  o.z = f2bf(tile[tc4 + 2][tr]);
  o.w = f2bf(tile[tc4 + 3][tr]);
  *(ushort4*)&dst[(size_t)(c0 + tr) * R + r0 + tc4] = o;
}

// ---------------- concat bias fill ----------------
__global__ __launch_bounds__(256) void biasfill_k(float* __restrict__ bh,
                                                  float* __restrict__ bq,
                                                  const float* __restrict__ bkr,
                                                  const float* __restrict__ bqr) {
  const int i = blockIdx.x * 256 + threadIdx.x;   // 0..3071
  if (i < 2560) bh[i] = (i >= 1536) ? bkr[i - 1536] : 0.f;
  bq[i] = (i >= 2048) ? bqr[i - 2048] : 0.f;
}

__device__ __forceinline__ float block_sum(float v, float* red) {
#pragma unroll
  for (int m = 32; m; m >>= 1) v += __shfl_xor(v, m);
  __syncthreads();
  if ((threadIdx.x & 63) == 0) red[threadIdx.x >> 6] = v;
  __syncthreads();
  return red[0] + red[1] + red[2] + red[3];
}

// ---------------- RMSNorm -> bf16 ----------------
__global__ __launch_bounds__(256) void rmsb_k(const float* __restrict__ x,
                                              const float* __restrict__ w,
                                              u16* __restrict__ out) {
  __shared__ float red[4];
  const int t = blockIdx.x, tid = threadIdx.x;
  const float* xr = x + (size_t)t * DM;
  float4 v0 = *(const float4*)&xr[tid * 4];
  float4 v1 = *(const float4*)&xr[1024 + tid * 4];
  float ss = v0.x*v0.x + v0.y*v0.y + v0.z*v0.z + v0.w*v0.w
           + v1.x*v1.x + v1.y*v1.y + v1.z*v1.z + v1.w*v1.w;
  float s = block_sum(ss, red);
  float r = rsqrtf(s * (1.0f / DM) + 1e-6f);
  float4 w0 = *(const float4*)&w[tid * 4];
  float4 w1 = *(const float4*)&w[1024 + tid * 4];
  u16* orow = out + (size_t)t * DM;
  ushort4 o0, o1;
  o0.x = f2bf(v0.x*r*w0.x); o0.y = f2bf(v0.y*r*w0.y);
  o0.z = f2bf(v0.z*r*w0.z); o0.w = f2bf(v0.w*r*w0.w);
  o1.x = f2bf(v1.x*r*w1.x); o1.y = f2bf(v1.y*r*w1.y);
  o1.z = f2bf(v1.z*r*w1.z); o1.w = f2bf(v1.w*r*w1.w);
  *(ushort4*)&orow[tid * 4] = o0;
  *(ushort4*)&orow[1024 + tid * 4] = o1;
}

// double RMS -> fp32 + bf16
__global__ __launch_bounds__(256) void rms2_k(const float* __restrict__ x,
                                              const float* __restrict__ w2,
                                              const float* __restrict__ wm,
                                              float* __restrict__ outf,
                                              u16* __restrict__ outb) {
  __shared__ float red[4];
  const int t = blockIdx.x, tid = threadIdx.x;
  const float* xr = x + (size_t)t * DM;
  float4 v0 = *(const float4*)&xr[tid * 4];
  float4 v1 = *(const float4*)&xr[1024 + tid * 4];
  float ss = v0.x*v0.x + v0.y*v0.y + v0.z*v0.z + v0.w*v0.w
           + v1.x*v1.x + v1.y*v1.y + v1.z*v1.z + v1.w*v1.w;
  float s1 = block_sum(ss, red);
  float r1 = rsqrtf(s1 * (1.0f / DM) + 1e-6f);
  float4 a0 = *(const float4*)&w2[tid * 4];
  float4 a1 = *(const float4*)&w2[1024 + tid * 4];
  float4 y0 = make_float4(v0.x*r1*a0.x, v0.y*r1*a0.y, v0.z*r1*a0.z, v0.w*r1*a0.w);
  float4 y1 = make_float4(v1.x*r1*a1.x, v1.y*r1*a1.y, v1.z*r1*a1.z, v1.w*r1*a1.w);
  float ss2 = y0.x*y0.x + y0.y*y0.y + y0.z*y0.z + y0.w*y0.w
            + y1.x*y1.x + y1.y*y1.y + y1.z*y1.z + y1.w*y1.w;
  float s2 = block_sum(ss2, red);
  float r2 = rsqrtf(s2 * (1.0f / DM) + 1e-6f);
  float4 b0 = *(const float4*)&wm[tid * 4];
  float4 b1 = *(const float4*)&wm[1024 + tid * 4];
  float4 z0 = make_float4(y0.x*r2*b0.x, y0.y*r2*b0.y, y0.z*r2*b0.z, y0.w*r2*b0.w);
  float4 z1 = make_float4(y1.x*r2*b1.x, y1.y*r2*b1.y, y1.z*r2*b1.z, y1.w*r2*b1.w);
  float* orow = outf + (size_t)t * DM;
  *(float4*)&orow[tid * 4] = z0;
  *(float4*)&orow[1024 + tid * 4] = z1;
  u16* brow = outb + (size_t)t * DM;
  ushort4 o0, o1;
  o0.x = f2bf(z0.x); o0.y = f2bf(z0.y); o0.z = f2bf(z0.z); o0.w = f2bf(z0.w);
  o1.x = f2bf(z1.x); o1.y = f2bf(z1.y); o1.z = f2bf(z1.z); o1.w = f2bf(z1.w);
  *(ushort4*)&brow[tid * 4] = o0;
  *(ushort4*)&brow[1024 + tid * 4] = o1;
}

// ---------------- bf16 MFMA GEMM, double-buffered global_load_lds (2-phase) ---------
// C(MxN) = A(MxK) * Bt(NxK)^T. 128x128 tile, BK=64, 4 waves, linear LDS.
// OUT: 0=f32, 1=bf16, 3=split (col<nsplit -> bf16 C; col>=nsplit -> bf16 transposed C2)
template <int ACT, bool BIAS, bool RES, int OUT>
__global__ __launch_bounds__(256, 2) void bgemm_k(const u16* __restrict__ A, int lda,
                                                  const u16* __restrict__ Bt, int ldb,
                                                  void* __restrict__ C, int ldc, int K,
                                                  const float* __restrict__ bias,
                                                  const float* __restrict__ res, int ldr,
                                                  void* __restrict__ C2, int ldc2, int nsplit) {
  __shared__ u16 As[2][128 * 64];
  __shared__ u16 Bs[2][128 * 64];
  const int tid = threadIdx.x;
  const int lane = tid & 63, w = tid >> 6;
  const int wr = w >> 1, wc = w & 1;
  const int l15 = lane & 15, l4 = lane >> 4;
  const int bm = blockIdx.y * 128, bn = blockIdx.x * 128;
  const int lrow = lane >> 3, lcol = (lane & 7) * 8;
  const u16* Abase = A + (size_t)(bm + w * 32 + lrow) * lda + lcol;
  const u16* Bbase = Bt + (size_t)(bn + w * 32 + lrow) * ldb + lcol;
  const int wofs = (w * 32) * 64;
  f4v acc[4][4] = {};
  // prologue: stage tile 0 into buffer 0
#pragma unroll
  for (int j = 0; j < 4; ++j) {
    gload16(Abase + (size_t)j * 8 * lda, &As[0][wofs + j * 8 * 64]);
    gload16(Bbase + (size_t)j * 8 * ldb, &Bs[0][wofs + j * 8 * 64]);
  }
  __syncthreads();
  const int nt = K >> 6;
  int cur = 0;
  for (int t = 0; t < nt; ++t) {
    if (t + 1 < nt) {
      const int k0 = (t + 1) << 6;
#pragma unroll
      for (int j = 0; j < 4; ++j) {
        gload16(Abase + (size_t)j * 8 * lda + k0, &As[cur ^ 1][wofs + j * 8 * 64]);
        gload16(Bbase + (size_t)j * 8 * ldb + k0, &Bs[cur ^ 1][wofs + j * 8 * 64]);
      }
    }
#pragma unroll
    for (int kk = 0; kk < 2; ++kk) {
      s8v af[4], bfr[4];
#pragma unroll
      for (int m = 0; m < 4; ++m)
        af[m] = *(const s8v*)(&As[cur][(wr * 64 + m * 16 + l15) * 64 + kk * 32 + l4 * 8]);
#pragma unroll
      for (int n = 0; n < 4; ++n)
        bfr[n] = *(const s8v*)(&Bs[cur][(wc * 64 + n * 16 + l15) * 64 + kk * 32 + l4 * 8]);
#pragma unroll
      for (int m = 0; m < 4; ++m)
#pragma unroll
        for (int n = 0; n < 4; ++n)
          acc[m][n] = mfma16(af[m], bfr[n], acc[m][n]);
    }
    __syncthreads();   // drains vmcnt(0): next buffer staged, current consumed
    cur ^= 1;
  }
#pragma unroll
  for (int m = 0; m < 4; ++m) {
    const int row0 = bm + wr * 64 + m * 16 + l4 * 4;
#pragma unroll
    for (int n = 0; n < 4; ++n) {
      const int col = bn + wc * 64 + n * 16 + l15;
      f4v v = acc[m][n];
      float bv = BIAS ? bias[col] : 0.0f;
      if (OUT == 3 && col >= nsplit) {
        ushort4 o;
        o.x = f2bf(v[0] + bv); o.y = f2bf(v[1] + bv);
        o.z = f2bf(v[2] + bv); o.w = f2bf(v[3] + bv);
        *(ushort4*)((u16*)C2 + (size_t)(col - nsplit) * ldc2 + row0) = o;
      } else {
#pragma unroll
        for (int r = 0; r < 4; ++r) {
          float o = v[r] + bv;
          if (RES) o += res[(size_t)(row0 + r) * ldr + col];
          if (ACT == 1) o = gelu_f(o);
          if (OUT == 0) ((float*)C)[(size_t)(row0 + r) * ldc + col] = o;
          else          ((u16*)C)[(size_t)(row0 + r) * ldc + col] = f2bf(o);
        }
      }
    }
  }
}

// ---------------- grouped expert bf16 GEMM (top-2 sparse), 2-phase dbuf ------------
template <bool GATHER, int ACT>
__global__ __launch_bounds__(256, 2) void bgemm_grp_k(const u16* __restrict__ A, int lda,
                                                      const u16* __restrict__ BtAll, int K, int N,
                                                      u16* __restrict__ C,
                                                      const float* __restrict__ biasAll,
                                                      const int* __restrict__ counts,
                                                      const int* __restrict__ bases,
                                                      const int* __restrict__ entry_token) {
  const int e = blockIdx.z;
  const int cnt = counts[e];
  const int m0 = blockIdx.y * 128;
  if (m0 >= cnt) return;
  const int base = bases[e];
  const u16* Bt = BtAll + (size_t)e * K * N;
  const float* bias = biasAll + (size_t)e * N;
  __shared__ u16 As[2][128 * 64];
  __shared__ u16 Bs[2][128 * 64];
  const int tid = threadIdx.x;
  const int lane = tid & 63, w = tid >> 6;
  const int wr = w >> 1, wc = w & 1;
  const int l15 = lane & 15, l4 = lane >> 4;
  const int bn = blockIdx.x * 128;
  const int lrow = lane >> 3, lcol = (lane & 7) * 8;
  int aro[4];
#pragma unroll
  for (int j = 0; j < 4; ++j) {
    int rr = m0 + w * 32 + j * 8 + lrow;
    if (rr >= cnt) rr = cnt - 1;
    aro[j] = GATHER ? entry_token[base + rr] : (base + rr);
  }
  const u16* Bbase = Bt + (size_t)(bn + w * 32 + lrow) * K + lcol;
  const int wofs = (w * 32) * 64;
  f4v acc[4][4] = {};
#pragma unroll
  for (int j = 0; j < 4; ++j) {
    gload16(A + (size_t)aro[j] * lda + lcol, &As[0][wofs + j * 8 * 64]);
    gload16(Bbase + (size_t)j * 8 * K, &Bs[0][wofs + j * 8 * 64]);
  }
  __syncthreads();
  const int nt = K >> 6;
  int cur = 0;
  for (int t = 0; t < nt; ++t) {
    if (t + 1 < nt) {
      const int k0 = (t + 1) << 6;
#pragma unroll
      for (int j = 0; j < 4; ++j) {
        gload16(A + (size_t)aro[j] * lda + k0 + lcol, &As[cur ^ 1][wofs + j * 8 * 64]);
        gload16(Bbase + (size_t)j * 8 * K + k0, &Bs[cur ^ 1][wofs + j * 8 * 64]);
      }
    }
#pragma unroll
    for (int kk = 0; kk < 2; ++kk) {
      s8v af[4], bfr[4];
#pragma unroll
      for (int m = 0; m < 4; ++m)
        af[m] = *(const s8v*)(&As[cur][(wr * 64 + m * 16 + l15) * 64 + kk * 32 + l4 * 8]);
#pragma unroll
      for (int n = 0; n < 4; ++n)
        bfr[n] = *(const s8v*)(&Bs[cur][(wc * 64 + n * 16 + l15) * 64 + kk * 32 + l4 * 8]);
#pragma unroll
      for (int m = 0; m < 4; ++m)
#pragma unroll
        for (int n = 0; n < 4; ++n)
          acc[m][n] = mfma16(af[m], bfr[n], acc[m][n]);
    }
    __syncthreads();
    cur ^= 1;
  }
#pragma unroll
  for (int m = 0; m < 4; ++m) {
    const int rl0 = m0 + wr * 64 + m * 16 + l4 * 4;
#pragma unroll
    for (int n = 0; n < 4; ++n) {
      const int col = bn + wc * 64 + n * 16 + l15;
      f4v v = acc[m][n];
      float bv = bias[col];
#pragma unroll
      for (int r = 0; r < 4; ++r) {
        const int rl = rl0 + r;
        if (rl < cnt) {
          float o = v[r] + bv;
          if (ACT == 1) o = gelu_f(o);
          C[(size_t)(base + rl) * N + col] = f2bf(o);
        }
      }
    }
  }
}

// ---------------- RoPE in place on bf16, both buffers in one launch ----------------
__global__ __launch_bounds__(256) void ropeb2_k(u16* __restrict__ qbuf, int ldq,
                                                u16* __restrict__ kbuf, int ldk,
                                                const float* __restrict__ cosb,
                                                const float* __restrict__ sinb) {
  const int gi = blockIdx.x * 256 + threadIdx.x;  // 0..2*TT*NH*32-1
  const int which = gi >> 20;                     // TT*NH*32 = 1<<20
  const int i = gi & ((1 << 20) - 1);
  u16* buf = which ? kbuf : qbuf;
  const int ldb = which ? ldk : ldq;
  const int t = i >> 9;
  const int rem = i & 511;
  const int hh2 = rem >> 5, p = rem & 31;
  const int s = t & (SEQ - 1);
  const float c = cosb[s * 32 + p], sn = sinb[s * 32 + p];
  unsigned* ptr = (unsigned*)(buf + (size_t)t * ldb + hh2 * 64 + p * 2);
  unsigned vv = *ptr;
  float x0 = bf2f((u16)(vv & 0xffffu)), x1 = bf2f((u16)(vv >> 16));
  float y0 = x0 * c - x1 * sn, y1 = x0 * sn + x1 * c;
  *ptr = (unsigned)f2bf(y0) | ((unsigned)f2bf(y1) << 16);
}

// ---------------- bf16 MFMA flash attention ----------------
__global__ __launch_bounds__(256) void attnb_k(const u16* __restrict__ qb, int ldq,
                                               const u16* __restrict__ qrb, int ldqr,
                                               const u16* __restrict__ kb, int ldk,
                                               const u16* __restrict__ krb, int ldkr,
                                               const u16* __restrict__ vt,
                                               u16* __restrict__ ob) {
  __shared__ u16 Ks[32 * 200];
  __shared__ u16 Vs[128 * 40];
  __shared__ u16 Ps[4][16 * 40];
  const int tid = threadIdx.x, lane = tid & 63, w = tid >> 6;
  const int l15 = lane & 15, l4 = lane >> 4;
  const int hh = blockIdx.y, bb = blockIdx.z;
  const int tbase = bb * SEQ;
  const int q0 = blockIdx.x * 64 + w * 16;
  const int qtok = tbase + q0 + l15;
  s8v aq[6];
#pragma unroll
  for (int kc = 0; kc < 4; ++kc)
    aq[kc] = *(const s8v*)(qb + (size_t)qtok * ldq + hh * 128 + kc * 32 + l4 * 8);
#pragma unroll
  for (int kc = 0; kc < 2; ++kc)
    aq[4 + kc] = *(const s8v*)(qrb + (size_t)qtok * ldqr + hh * 64 + kc * 32 + l4 * 8);
  f4v o[8] = {};
  float m_run[4] = {-1e30f, -1e30f, -1e30f, -1e30f};
  float l_run[4] = {0.f, 0.f, 0.f, 0.f};
  for (int kt = 0; kt < SEQ / 32; ++kt) {
    __syncthreads();
#pragma unroll
    for (int i = 0; i < 3; ++i) {                 // stage K-concat: 32 x 192
      int q = i * 256 + tid;
      int row = q / 24, c = q % 24;
      int tok = tbase + kt * 32 + row;
      s8v v;
      if (c < 16) v = *(const s8v*)(kb  + (size_t)tok * ldk + hh * 128 + c * 8);
      else        v = *(const s8v*)(krb + (size_t)tok * ldkr + hh * 64 + (c - 16) * 8);
      *(s8v*)(Ks + row * 200 + c * 8) = v;
    }
#pragma unroll
    for (int i = 0; i < 2; ++i) {                 // stage V^T: 128 x 32
      int q = i * 256 + tid;
      int row = q >> 2, c = q & 3;
      s8v v = *(const s8v*)(vt + (size_t)(hh * 128 + row) * 2048 + tbase + kt * 32 + c * 8);
      *(s8v*)(Vs + row * 40 + c * 8) = v;
    }
    __syncthreads();
    f4v s0 = {}, s1 = {};
#pragma unroll
    for (int kc = 0; kc < 6; ++kc) {              // S = Q K^T (two 16-col tiles)
      s8v bk0 = *(const s8v*)(Ks + l15 * 200 + kc * 32 + l4 * 8);
      s8v bk1 = *(const s8v*)(Ks + (16 + l15) * 200 + kc * 32 + l4 * 8);
      s0 = mfma16(aq[kc], bk0, s0);
      s1 = mfma16(aq[kc], bk1, s1);
    }
    float scf[4];
#pragma unroll
    for (int r = 0; r < 4; ++r) {                 // online softmax, rows (l4*4+r)
      float a = s0[r] * ATT_SCALE, b = s1[r] * ATT_SCALE;
      float mt = fmaxf(a, b);
#pragma unroll
      for (int msk = 1; msk < 16; msk <<= 1) mt = fmaxf(mt, __shfl_xor(mt, msk));
      float mn = fmaxf(m_run[r], mt);
      float p0 = __expf(a - mn), p1 = __expf(b - mn);
      float rs = p0 + p1;
#pragma unroll
      for (int msk = 1; msk < 16; msk <<= 1) rs += __shfl_xor(rs, msk);
      float sc = __expf(m_run[r] - mn);
      l_run[r] = l_run[r] * sc + rs;
      m_run[r] = mn;
      scf[r] = sc;
      int rq = l4 * 4 + r;
      Ps[w][rq * 40 + l15] = f2bf(p0);
      Ps[w][rq * 40 + 16 + l15] = f2bf(p1);
    }
#pragma unroll
    for (int dt = 0; dt < 8; ++dt) {
      o[dt][0] *= scf[0]; o[dt][1] *= scf[1];
      o[dt][2] *= scf[2]; o[dt][3] *= scf[3];
    }
    s8v pa = *(const s8v*)(&Ps[w][l15 * 40 + l4 * 8]);
#pragma unroll
    for (int dt = 0; dt < 8; ++dt) {              // O += P V
      s8v bv = *(const s8v*)(Vs + (dt * 16 + l15) * 40 + l4 * 8);
      o[dt] = mfma16(pa, bv, o[dt]);
    }
  }
  float linv[4];
#pragma unroll
  for (int r = 0; r < 4; ++r) linv[r] = 1.0f / l_run[r];
#pragma unroll
  for (int dt = 0; dt < 8; ++dt)
#pragma unroll
    for (int r = 0; r < 4; ++r)
      ob[(size_t)(tbase + q0 + l4 * 4 + r) * 2048 + hh * 128 + dt * 16 + l15] =
          f2bf(o[dt][r] * linv[r]);
}

// ---------------- router ----------------
__global__ __launch_bounds__(256) void router_k(const float* __restrict__ hn,
                                                const float* __restrict__ cent,
                                                int* __restrict__ topk_idx,
                                                float* __restrict__ topk_w,
                                                int* __restrict__ pos,
                                                int* __restrict__ counts) {
  const int t = blockIdx.x, tid = threadIdx.x;
  float p[NE] = {};
  const float* xr = hn + (size_t)t * DM;
  for (int d = tid * 4; d < DM; d += 1024) {
    float4 xv = *(const float4*)&xr[d];
#pragma unroll
    for (int e = 0; e < NE; ++e) {
      float4 cv = *(const float4*)&cent[e * DM + d];
      p[e] += xv.x * cv.x + xv.y * cv.y + xv.z * cv.z + xv.w * cv.w;
    }
  }
  __shared__ float wred[NE][4];
#pragma unroll
  for (int e = 0; e < NE; ++e) {
    float v = p[e];
#pragma unroll
    for (int m = 32; m; m >>= 1) v += __shfl_xor(v, m);
    if ((tid & 63) == 0) wred[e][tid >> 6] = v;
  }
  __syncthreads();
  if (tid == 0) {
    float lg[NE], mx = -3.0e38f;
    for (int e = 0; e < NE; ++e) {
      lg[e] = wred[e][0] + wred[e][1] + wred[e][2] + wred[e][3];
      mx = fmaxf(mx, lg[e]);
    }
    float pe[NE], sum = 0.f;
    for (int e = 0; e < NE; ++e) { pe[e] = expf(lg[e] - mx); sum += pe[e]; }
    const float inv = 1.f / sum;
    int i0 = 0; float v0 = -1.f;
    for (int e = 0; e < NE; ++e) { float a = pe[e] * inv; if (a > v0) { v0 = a; i0 = e; } }
    int i1 = 0; float v1 = -1.f;
    for (int e = 0; e < NE; ++e) { if (e == i0) continue; float a = pe[e] * inv; if (a > v1) { v1 = a; i1 = e; } }
    topk_idx[t * 2 + 0] = i0;
    topk_idx[t * 2 + 1] = i1;
    topk_w[t * 2 + 0] = v0;
    topk_w[t * 2 + 1] = v1;
    pos[t * 2 + 0] = atomicAdd(&counts[i0], 1);
    pos[t * 2 + 1] = atomicAdd(&counts[i1], 1);
  }
}

// ---------------- prefix + scatter ----------------
__global__ __launch_bounds__(256) void scatter_k(const int* __restrict__ topk_idx,
                                                 const int* __restrict__ pos,
                                                 const int* __restrict__ counts,
                                                 int* __restrict__ bases,
                                                 int* __restrict__ entry_token,
                                                 int* __restrict__ token_entry) {
  __shared__ int sb[NE];
  const int tid = threadIdx.x;
  if (tid == 0) {
    int acc = 0;
    for (int e = 0; e < NE; ++e) { sb[e] = acc; bases[e] = acc; acc += counts[e]; }
  }
  __syncthreads();
  for (int i = tid; i < TT * 2; i += 256) {
    const int e = topk_idx[i];
    const int entry = sb[e] + pos[i];
    entry_token[entry] = i >> 1;
    token_entry[i] = entry;
  }
}

// ---------------- combine ----------------
__global__ __launch_bounds__(256) void combine_k(const float* __restrict__ x2,
                                                 const float* __restrict__ hn,
                                                 const float* __restrict__ sh,
                                                 const u16* __restrict__ oute,
                                                 const int* __restrict__ token_entry,
                                                 const float* __restrict__ topk_w,
                                                 float* __restrict__ out) {
  const int i = blockIdx.x * 256 + threadIdx.x;
  const int t = i >> 9;
  const int c = (i & 511) * 4;
  const int e0 = token_entry[t * 2 + 0], e1 = token_entry[t * 2 + 1];
  const float w0 = topk_w[t * 2 + 0], w1 = topk_w[t * 2 + 1];
  float4 a = *(const float4*)&x2[(size_t)t * DM + c];
  float4 b = *(const float4*)&hn[(size_t)t * DM + c];
  float4 s = *(const float4*)&sh[(size_t)t * DM + c];
  ushort4 u0 = *(const ushort4*)&oute[(size_t)e0 * DM + c];
  ushort4 u1 = *(const ushort4*)&oute[(size_t)e1 * DM + c];
  *(float4*)&out[(size_t)t * DM + c] =
      make_float4(a.x + b.x + s.x + w0 * bf2f(u0.x) + w1 * bf2f(u1.x),
                  a.y + b.y + s.y + w0 * bf2f(u0.y) + w1 * bf2f(u1.y),
                  a.z + b.z + s.z + w0 * bf2f(u0.z) + w1 * bf2f(u1.z),
                  a.w + b.w + s.w + w0 * bf2f(u0.w) + w1 * bf2f(u1.w));
}

// ---------------- host ----------------
extern "C" void kernel_launch(void* const* d_in, const int* in_sizes, int n_in,
                              void* d_out, int out_size, void* d_ws, size_t ws_size,
                              hipStream_t stream) {
  (void)in_sizes; (void)n_in; (void)out_size; (void)ws_size;
  const float* x       = (const float*)d_in[0];
  const float* fc      = (const float*)d_in[1];
  const float* fs      = (const float*)d_in[2];
  const float* w_norm1 = (const float*)d_in[3];
  const float* w_lq    = (const float*)d_in[4];
  const float* w_lkv   = (const float*)d_in[5];
  const float* w_q     = (const float*)d_in[6];
  const float* w_k     = (const float*)d_in[7];
  const float* w_v     = (const float*)d_in[8];
  const float* w_qr    = (const float*)d_in[9];
  const float* b_qr    = (const float*)d_in[10];
  const float* w_kr    = (const float*)d_in[11];
  const float* b_kr    = (const float*)d_in[12];
  const float* w_o     = (const float*)d_in[13];
  const float* b_o     = (const float*)d_in[14];
  const float* w_norm2 = (const float*)d_in[15];
  const float* w_moe   = (const float*)d_in[16];
  const float* cent    = (const float*)d_in[17];
  const float* ws1     = (const float*)d_in[18];
  const float* bs1     = (const float*)d_in[19];
  const float* ws2     = (const float*)d_in[20];
  const float* bs2     = (const float*)d_in[21];
  const float* wr1     = (const float*)d_in[22];
  const float* br1     = (const float*)d_in[23];
  const float* wr2     = (const float*)d_in[24];
  const float* br2     = (const float*)d_in[25];
  float* out = (float*)d_out;

  char* W = (char*)d_ws;
  // persistent transposed bf16 weights [0,100MB)
  u16* wt_h   = (u16*)(W + (size_t)0  * MB_);   // [2560][2048]: lq|lkv|kr
  u16* wt_qqr = (u16*)(W + (size_t)10 * MB_);   // [3072][1024]: q|qr
  u16* wt_kv  = (u16*)(W + (size_t)16 * MB_);   // [4096][512]:  k|v
  u16* wt_o   = (u16*)(W + (size_t)20 * MB_);   // [2048][2048]
  u16* wt_s1  = (u16*)(W + (size_t)28 * MB_);   // [1024][2048]
  u16* wt_s2  = (u16*)(W + (size_t)32 * MB_);   // [2048][1024]
  u16* wt_r1  = (u16*)(W + (size_t)36 * MB_);   // 8x[1024][2048]
  u16* wt_r2  = (u16*)(W + (size_t)68 * MB_);   // 8x[2048][1024]
  // phase A activations
  u16* h_bf   = (u16*)(W + (size_t)100 * MB_);  // [2048][2048]
  u16* hp     = (u16*)(W + (size_t)108 * MB_);  // [2048][2560]: cq|ckv|kr
  u16* qp     = (u16*)(W + (size_t)118 * MB_);  // [2048][3072]: q|qr
  u16* kbuf   = (u16*)(W + (size_t)130 * MB_);  // [2048][2048]
  u16* vbuf_t = (u16*)(W + (size_t)138 * MB_);  // [2048 dv][2048 tok]
  u16* obuf   = (u16*)(W + (size_t)146 * MB_);  // [2048][2048]
  // phase B activations (alias dead phase-A buffers)
  float* x2   = (float*)(W + (size_t)100 * MB_);
  float* hn   = (float*)(W + (size_t)116 * MB_);
  u16* hn_bf  = (u16*)(W + (size_t)132 * MB_);
  u16* s1b    = (u16*)(W + (size_t)140 * MB_);
  float* shb  = (float*)(W + (size_t)144 * MB_);
  u16* midb   = (u16*)(W + (size_t)160 * MB_);
  u16* oute   = (u16*)(W + (size_t)168 * MB_);
  int* ip          = (int*)(W + (size_t)184 * MB_);
  int* counts      = ip;
  int* bases       = ip + 8;
  int* topk_idx    = ip + 16;
  int* pos         = ip + 16 + 4096;
  int* token_entry = ip + 16 + 8192;
  int* entry_token = ip + 16 + 12288;
  float* topk_w    = (float*)(ip + 16 + 16384);
  float* bias_h    = (float*)(ip + 16 + 20480);   // [2560]
  float* bias_q    = bias_h + 2560;               // [3072]

  // 0. batched weight transpose+cast (single launch, 51200 tiles)
  TDs P;
  P.d[0]  = {w_lq,  wt_h,               2048, 1024, 0};
  P.d[1]  = {w_lkv, wt_h + 1024 * 2048, 2048, 512,  2048};
  P.d[2]  = {w_kr,  wt_h + 1536 * 2048, 2048, 1024, 3072};
  P.d[3]  = {w_q,   wt_qqr,             1024, 2048, 5120};
  P.d[4]  = {w_qr,  wt_qqr + 2048*1024, 1024, 1024, 7168};
  P.d[5]  = {w_k,   wt_kv,              512,  2048, 8192};
  P.d[6]  = {w_v,   wt_kv + 2048*512,   512,  2048, 9216};
  P.d[7]  = {w_o,   wt_o,               2048, 2048, 10240};
  P.d[8]  = {ws1,   wt_s1,              2048, 1024, 14336};
  P.d[9]  = {ws2,   wt_s2,              1024, 2048, 16384};
  P.d[10] = {wr1,   wt_r1,              2048, 1024, 18432};   // 8 batches
  P.d[11] = {wr2,   wt_r2,              1024, 2048, 34816};   // 8 batches
  tcastb_k<<<51200, 256, 0, stream>>>(P);
  biasfill_k<<<12, 256, 0, stream>>>(bias_h, bias_q, b_kr, b_qr);

  // 1. h = rms(x, w_norm1) -> bf16
  rmsb_k<<<TT, 256, 0, stream>>>(x, w_norm1, h_bf);
  // 2. fused G1: h -> [cq | ckv | kr]  (N=2560, K=2048)
  bgemm_k<0, true, false, 1><<<dim3(20, 16), 256, 0, stream>>>(
      h_bf, 2048, wt_h, 2048, hp, 2560, 2048, bias_h, nullptr, 0, nullptr, 0, 0);
  // 3. fused G2: cq -> [q | qr]  (N=3072, K=1024)
  bgemm_k<0, true, false, 1><<<dim3(24, 16), 256, 0, stream>>>(
      hp, 2560, wt_qqr, 1024, qp, 3072, 1024, bias_q, nullptr, 0, nullptr, 0, 0);
  // 4. fused G3: ckv -> [k | v^T]  (N=4096, K=512, split epilogue)
  bgemm_k<0, false, false, 3><<<dim3(32, 16), 256, 0, stream>>>(
      hp + 1024, 2560, wt_kv, 512, kbuf, 2048, 512, nullptr, nullptr, 0, vbuf_t, 2048, 2048);
  // 5. RoPE on qr (qp cols 2048+) and kr (hp cols 1536+), one launch
  ropeb2_k<<<8192, 256, 0, stream>>>(qp + 2048, 3072, hp + 1536, 2560, fc, fs);
  // 6. attention
  attnb_k<<<dim3(16, NH, 2), 256, 0, stream>>>(qp, 3072, qp + 2048, 3072,
                                               kbuf, 2048, hp + 1536, 2560, vbuf_t, obuf);
  // 7. x2 = x + o @ w_o + b_o
  bgemm_k<0, true, true, 0><<<dim3(16, 16), 256, 0, stream>>>(
      obuf, 2048, wt_o, 2048, x2, 2048, 2048, b_o, x, 2048, nullptr, 0, 0);
  // 8. hn = rms(rms(x2))
  rms2_k<<<TT, 256, 0, stream>>>(x2, w_norm2, w_moe, hn, hn_bf);
  // 9-10. shared FFN
  bgemm_k<0, true, false, 1><<<dim3(8, 16), 256, 0, stream>>>(
      hn_bf, 2048, wt_s1, 2048, s1b, 1024, 2048, bs1, nullptr, 0, nullptr, 0, 0);
  bgemm_k<1, true, false, 0><<<dim3(16, 16), 256, 0, stream>>>(
      s1b, 1024, wt_s2, 1024, shb, 2048, 1024, bs2, nullptr, 0, nullptr, 0, 0);
  // 11-12. router + scatter
  hipMemsetAsync(counts, 0, NE * sizeof(int), stream);
  router_k<<<TT, 256, 0, stream>>>(hn, cent, topk_idx, topk_w, pos, counts);
  scatter_k<<<1, 256, 0, stream>>>(topk_idx, pos, counts, bases, entry_token, token_entry);
  // 13-14. grouped expert GEMMs
  bgemm_grp_k<true, 0><<<dim3(8, 32, NE), 256, 0, stream>>>(
      hn_bf, 2048, wt_r1, 2048, 1024, midb, br1, counts, bases, entry_token);
  bgemm_grp_k<false, 1><<<dim3(16, 32, NE), 256, 0, stream>>>(
      midb, 1024, wt_r2, 1024, 2048, oute, br2, counts, bases, nullptr);
  // 15. combine
  combine_k<<<4096, 256, 0, stream>>>(x2, hn, shb, oute, token_entry, topk_w, out);
}